// Round 24
// baseline (832.142 us; speedup 1.0000x reference)
//
#include <hip/hip_runtime.h>
#include <math.h>
#include <stdint.h>

#define TOKS 8192
#define HDIM 768
#define FDIM 3072
#define NEXP 8
#define NHEAD 12
#define SEQ 1024
#define BATCH 8
#define PERMSZ 9216   // 8192 + 8*128 worst-case padding

typedef __attribute__((ext_vector_type(8))) short s16x8;   // 8 bf16 = 4 VGPR
typedef __attribute__((ext_vector_type(4))) short s16x4;
typedef __attribute__((ext_vector_type(4))) float f32x4;

__device__ __forceinline__ short f2bf(float f) {
  uint32_t u = __float_as_uint(f);
  uint32_t r = (u + 0x7fffu + ((u >> 16) & 1u)) >> 16;   // RTN-even
  return (short)(r & 0xffffu);
}
__device__ __forceinline__ float bf2f(short h) {
  return __uint_as_float(((uint32_t)(uint16_t)h) << 16);
}
__device__ __forceinline__ void gload16(const void* g, void* l) {
  __builtin_amdgcn_global_load_lds(
      (const __attribute__((address_space(1))) uint32_t*)g,
      (__attribute__((address_space(3))) uint32_t*)l, 16, 0, 0);
}
// drain outstanding global->LDS DMA, then workgroup barrier.
__device__ __forceinline__ void pipe_wait_barrier() {
  asm volatile("s_waitcnt vmcnt(0)" ::: "memory");
  __builtin_amdgcn_s_barrier();
}
// LDS-reads-retired fence + raw barrier (no vmcnt drain — keeps DMA in flight).
__device__ __forceinline__ void lds_read_barrier() {
  asm volatile("s_waitcnt lgkmcnt(0)" ::: "memory");
  __builtin_amdgcn_s_barrier();
}

// ============ f32 -> (hi,lo) bf16 split, 4 elems/thread ============
__global__ __launch_bounds__(256) void convert_split(
    const float* __restrict__ X, short* __restrict__ Xh, short* __restrict__ Xl, int n4)
{
  const int i = blockIdx.x * 256 + threadIdx.x;
  if (i >= n4) return;
  const float4 v = ((const float4*)X)[i];
  const float a[4] = {v.x, v.y, v.z, v.w};
  s16x4 h, l;
#pragma unroll
  for (int j = 0; j < 4; ++j) {
    h[j] = f2bf(a[j]);
    l[j] = f2bf(a[j] - bf2f(h[j]));
  }
  ((s16x4*)Xh)[i] = h;
  ((s16x4*)Xl)[i] = l;
}

// ============ transpose + split: WT{h,l}[n][k] = split(W[k][n]) ============
__global__ __launch_bounds__(256) void transpose_split(
    const float* __restrict__ W, short* __restrict__ WTh, short* __restrict__ WTl,
    int K, int N)
{
  __shared__ float t[32][33];
  const int tid = threadIdx.x;
  const int tx = tid & 31, ty = tid >> 5;
  const int n0 = blockIdx.x * 32, k0 = blockIdx.y * 32;
#pragma unroll
  for (int r = 0; r < 4; ++r)
    t[ty + r * 8][tx] = W[(size_t)(k0 + ty + r * 8) * N + n0 + tx];
  __syncthreads();
#pragma unroll
  for (int r = 0; r < 4; ++r) {
    const float v = t[tx][ty + r * 8];
    const short h = f2bf(v);
    WTh[(size_t)(n0 + ty + r * 8) * K + k0 + tx] = h;
    WTl[(size_t)(n0 + ty + r * 8) * K + k0 + tx] = f2bf(v - bf2f(h));
  }
}

// ============ QKV split-GEMM: depth-2 counted-vmcnt pipeline (64 KB LDS),
// raw barriers (no vmcnt drain mid-loop); XCD-swizzled grid; Q pre-scaled 1/8. ====
__global__ __launch_bounds__(256) void qkv_split_mfma(
    const short* __restrict__ Ah, const short* __restrict__ Al,
    const short* __restrict__ BhT, const short* __restrict__ BlT,
    const float* __restrict__ bias,
    short* __restrict__ QKh, short* __restrict__ QKl,
    short* __restrict__ VTh, short* __restrict__ VTl)
{
  const int K = 768;
  __shared__ __align__(16) short lAh[2][4096];
  __shared__ __align__(16) short lAl[2][4096];
  __shared__ __align__(16) short lBh[2][4096];
  __shared__ __align__(16) short lBl[2][4096];
  // XCD swizzle: nwg = 18*64 = 1152, chunk = 144 per XCD (bijective)
  const int dsp = blockIdx.x + 18 * blockIdx.y;
  const int orig = (dsp & 7) * 144 + (dsp >> 3);
  const int bx = orig % 18, by = orig / 18;
  const int tid = threadIdx.x;
  const int w = tid >> 6, lane = tid & 63;
  const int wr = w >> 1, wc = w & 1;
  const int row0 = by * 128, col0 = bx * 128;
  const int sr = lane & 15, kg = lane >> 4;
  const size_t a0 = (size_t)(row0 + 2 * w * 16 + sr) * K + kg * 8;
  const size_t a1 = a0 + (size_t)16 * K;
  const size_t b0 = (size_t)(col0 + 2 * w * 16 + sr) * K + kg * 8;
  const size_t b1 = b0 + (size_t)16 * K;
  const int d0 = (2 * w) * 512, d1 = (2 * w + 1) * 512;
#define STAGE_Q(bu, k0) do { \
    gload16(Ah + a0 + (k0), &lAh[bu][d0]); \
    gload16(Ah + a1 + (k0), &lAh[bu][d1]); \
    gload16(Al + a0 + (k0), &lAl[bu][d0]); \
    gload16(Al + a1 + (k0), &lAl[bu][d1]); \
    gload16(BhT + b0 + (k0), &lBh[bu][d0]); \
    gload16(BhT + b1 + (k0), &lBh[bu][d1]); \
    gload16(BlT + b0 + (k0), &lBl[bu][d0]); \
    gload16(BlT + b1 + (k0), &lBl[bu][d1]); \
  } while (0)
  f32x4 acc[4][4] = {};
  STAGE_Q(0, 0);
  STAGE_Q(1, 32);
  asm volatile("s_waitcnt vmcnt(8)" ::: "memory");   // stage(0) landed; stage(1) in flight
  __builtin_amdgcn_s_barrier();
  for (int t = 0; t < 24; ++t) {
    const int cur = t & 1;
    s16x8 ah[4], al[4], bh[4], bl[4];
#pragma unroll
    for (int i = 0; i < 4; ++i) {
      ah[i] = *(const s16x8*)&lAh[cur][(wr * 4 + i) * 512 + lane * 8];
      al[i] = *(const s16x8*)&lAl[cur][(wr * 4 + i) * 512 + lane * 8];
      bh[i] = *(const s16x8*)&lBh[cur][(wc * 4 + i) * 512 + lane * 8];
      bl[i] = *(const s16x8*)&lBl[cur][(wc * 4 + i) * 512 + lane * 8];
    }
    lds_read_barrier();   // reads retired; buf[cur] free (DMA stays in flight!)
    if (t + 2 < 24) STAGE_Q(cur, (t + 2) * 32);   // depth-2 prefetch into freed buffer
#pragma unroll
    for (int mi = 0; mi < 4; ++mi)
#pragma unroll
      for (int ni = 0; ni < 4; ++ni) {
        acc[mi][ni] = __builtin_amdgcn_mfma_f32_16x16x32_bf16(ah[mi], bh[ni], acc[mi][ni], 0, 0, 0);
        acc[mi][ni] = __builtin_amdgcn_mfma_f32_16x16x32_bf16(ah[mi], bl[ni], acc[mi][ni], 0, 0, 0);
        acc[mi][ni] = __builtin_amdgcn_mfma_f32_16x16x32_bf16(al[mi], bh[ni], acc[mi][ni], 0, 0, 0);
      }
    // counted wait: stage(t+1) done, stage(t+2)'s 8 loads remain outstanding
    if (t + 2 < 24) asm volatile("s_waitcnt vmcnt(8)" ::: "memory");
    else            asm volatile("s_waitcnt vmcnt(0)" ::: "memory");
    __builtin_amdgcn_s_barrier();
  }
#undef STAGE_Q
  const int cl = lane & 15, rg = lane >> 4;
#pragma unroll
  for (int mi = 0; mi < 4; ++mi)
#pragma unroll
    for (int ni = 0; ni < 4; ++ni) {
      const int c = col0 + wc * 64 + ni * 16 + cl;
      const int rowb = row0 + wr * 64 + mi * 16 + rg * 4;
      // Q columns (c<768) pre-scaled by 1/8: exact power-of-2, commutes through
      // the bf16 split and the QK^T MFMA bit-exactly.
      const float qscale = (c < 768) ? 0.125f : 1.0f;
      s16x4 hv, lv;
#pragma unroll
      for (int r = 0; r < 4; ++r) {
        const float v = (acc[mi][ni][r] + bias[c]) * qscale;
        const short hh = f2bf(v);
        hv[r] = hh;
        lv[r] = f2bf(v - bf2f(hh));
      }
      if (c < 1536) {
#pragma unroll
        for (int r = 0; r < 4; ++r) {
          QKh[(size_t)(rowb + r) * 1536 + c] = hv[r];
          QKl[(size_t)(rowb + r) * 1536 + c] = lv[r];
        }
      } else {          // V column: transposed store VT[b][h][d][s]
        const int dall = c - 1536;
        const size_t vi = (((size_t)((rowb >> 10) * NHEAD + (dall >> 6))) * 64 + (dall & 63)) * 1024
                          + (rowb & 1023);
        *(s16x4*)(VTh + vi) = hv;
        *(s16x4*)(VTl + vi) = lv;
      }
    }
}

// ============ AO GEMM: depth-2 counted-vmcnt split-bf16 (64 KB LDS), SPLIT-K x2 ====
__global__ __launch_bounds__(256) void gemm_splitk_staged(
    const short* __restrict__ Ah, const short* __restrict__ Al,
    const short* __restrict__ BhT, const short* __restrict__ BlT,
    const float* __restrict__ bias, float* __restrict__ C0, float* __restrict__ C1,
    int N, int K)
{
  __shared__ __align__(16) short lAh[2][4096];
  __shared__ __align__(16) short lAl[2][4096];
  __shared__ __align__(16) short lBh[2][4096];
  __shared__ __align__(16) short lBl[2][4096];
  const int tid = threadIdx.x;
  const int w = tid >> 6, lane = tid & 63;
  const int wr = w >> 1, wc = w & 1;
  const int row0 = blockIdx.y * 128, col0 = blockIdx.x * 128;
  const int z = blockIdx.z;
  const int Khalf = K >> 1, koff = z * Khalf;
  const int sr = lane & 15, kg = lane >> 4;
  const size_t a0 = (size_t)(row0 + 2 * w * 16 + sr) * K + koff + kg * 8;
  const size_t a1 = a0 + (size_t)16 * K;
  const size_t b0 = (size_t)(col0 + 2 * w * 16 + sr) * K + koff + kg * 8;
  const size_t b1 = b0 + (size_t)16 * K;
  const int d0 = (2 * w) * 512, d1 = (2 * w + 1) * 512;
#define STAGE_K4(bu, k0) do { \
    gload16(Ah + a0 + (k0), &lAh[bu][d0]); \
    gload16(Ah + a1 + (k0), &lAh[bu][d1]); \
    gload16(Al + a0 + (k0), &lAl[bu][d0]); \
    gload16(Al + a1 + (k0), &lAl[bu][d1]); \
    gload16(BhT + b0 + (k0), &lBh[bu][d0]); \
    gload16(BhT + b1 + (k0), &lBh[bu][d1]); \
    gload16(BlT + b0 + (k0), &lBl[bu][d0]); \
    gload16(BlT + b1 + (k0), &lBl[bu][d1]); \
  } while (0)
  f32x4 acc[4][4] = {};
  const int NT = Khalf >> 5;
  STAGE_K4(0, 0);
  STAGE_K4(1, 32);
  asm volatile("s_waitcnt vmcnt(8)" ::: "memory");
  __builtin_amdgcn_s_barrier();
  for (int t = 0; t < NT; ++t) {
    const int cur = t & 1;
    s16x8 ah[4], al[4], bh[4], bl[4];
#pragma unroll
    for (int i = 0; i < 4; ++i) {
      ah[i] = *(const s16x8*)&lAh[cur][(wr * 4 + i) * 512 + lane * 8];
      al[i] = *(const s16x8*)&lAl[cur][(wr * 4 + i) * 512 + lane * 8];
      bh[i] = *(const s16x8*)&lBh[cur][(wc * 4 + i) * 512 + lane * 8];
      bl[i] = *(const s16x8*)&lBl[cur][(wc * 4 + i) * 512 + lane * 8];
    }
    lds_read_barrier();
    if (t + 2 < NT) STAGE_K4(cur, (t + 2) * 32);
#pragma unroll
    for (int mi = 0; mi < 4; ++mi)
#pragma unroll
      for (int ni = 0; ni < 4; ++ni) {
        acc[mi][ni] = __builtin_amdgcn_mfma_f32_16x16x32_bf16(ah[mi], bh[ni], acc[mi][ni], 0, 0, 0);
        acc[mi][ni] = __builtin_amdgcn_mfma_f32_16x16x32_bf16(ah[mi], bl[ni], acc[mi][ni], 0, 0, 0);
        acc[mi][ni] = __builtin_amdgcn_mfma_f32_16x16x32_bf16(al[mi], bh[ni], acc[mi][ni], 0, 0, 0);
      }
    if (t + 2 < NT) asm volatile("s_waitcnt vmcnt(8)" ::: "memory");
    else            asm volatile("s_waitcnt vmcnt(0)" ::: "memory");
    __builtin_amdgcn_s_barrier();
  }
#undef STAGE_K4
  float* C = z ? C1 : C0;
  const int cl = lane & 15, rg = lane >> 4;
#pragma unroll
  for (int mi = 0; mi < 4; ++mi)
#pragma unroll
    for (int r = 0; r < 4; ++r) {
      const int row = row0 + wr * 64 + mi * 16 + rg * 4 + r;
#pragma unroll
      for (int ni = 0; ni < 4; ++ni) {
        const int c = col0 + wc * 64 + ni * 16 + cl;
        C[(size_t)row * N + c] = acc[mi][ni][r] + (z ? 0.f : bias[c]);
      }
    }
}

// ============ MFMA flash attention, KV-SPLIT x2 — TWO-WAVE blocks (10 KB LDS) ============
// P plain bf16; QK^T uses (Qh+Ql)*Kh only (Kl dropped: S err ~3e-3 abs, averaged to
// ~1e-4 in O by softmax over ~900 keys — router-safe class, same as bf16-P change).
__global__ __launch_bounds__(128, 2) void attention_part(
    const short* __restrict__ QKh, const short* __restrict__ QKl,
    const short* __restrict__ VTh, const short* __restrict__ VTl,
    float* __restrict__ O0, float* __restrict__ O1,
    float2* __restrict__ ml0, float2* __restrict__ ml1)
{
  __shared__ __align__(16) short lPh[2][2560];   // [wave][(mi*2+ks2)*640 + q*40 + koff]
  const int tid = threadIdx.x;
  const int w = tid >> 6, lane = tid & 63;
  // XCD swizzle: nwg = 32*12*8 = 3072, chunk = 384 (= one batch per XCD)
  const int dsp = blockIdx.x + 32 * (blockIdx.y + 12 * blockIdx.z);
  const int orig = (dsp & 7) * 384 + (dsp >> 3);
  const int wx = orig & 31;
  const int b = orig / 384, h = (orig >> 5) % 12;
  const int z = wx & 1;
  const int q0 = (wx >> 1) * 64 + w * 32;    // this wave's 32 q-rows
  const int kv0 = z * 512;
  const int sr = lane & 15, kg = lane >> 4;
  const int cl = sr, rg = kg;
  short* myPh = lPh[w];
  float* Op = z ? O1 : O0;
  float2* mlp = z ? ml1 : ml0;

  s16x8 qh[2][2], ql[2][2];
  {
    const size_t qbase = ((size_t)b * SEQ + q0 + sr) * 1536 + h * 64 + kg * 8;
#pragma unroll
    for (int mi = 0; mi < 2; ++mi)
#pragma unroll
      for (int ks = 0; ks < 2; ++ks) {
        const size_t o = qbase + (size_t)mi * (16 * 1536) + ks * 32;
        qh[mi][ks] = *(const s16x8*)(QKh + o);
        ql[mi][ks] = *(const s16x8*)(QKl + o);
      }
  }
  float m_run[2][4], l_run[2][4];
#pragma unroll
  for (int mi = 0; mi < 2; ++mi)
#pragma unroll
    for (int r = 0; r < 4; ++r) { m_run[mi][r] = -3.0e38f; l_run[mi][r] = 0.f; }
  f32x4 acc_o[2][4] = {};

  for (int kt = kv0; kt < kv0 + 512; kt += 64) {
    s16x8 kh[4][2];
    {
      const size_t kbase = ((size_t)b * SEQ + kt + sr) * 1536 + 768 + h * 64 + kg * 8;
#pragma unroll
      for (int ni = 0; ni < 4; ++ni)
#pragma unroll
        for (int ks = 0; ks < 2; ++ks) {
          const size_t o = kbase + (size_t)ni * (16 * 1536) + ks * 32;
          kh[ni][ks] = *(const s16x8*)(QKh + o);
        }
    }
    f32x4 accs[2][4] = {};
    __builtin_amdgcn_s_setprio(1);
#pragma unroll
    for (int ks = 0; ks < 2; ++ks)
#pragma unroll
      for (int ni = 0; ni < 4; ++ni)
#pragma unroll
        for (int mi = 0; mi < 2; ++mi) {
          accs[mi][ni] = __builtin_amdgcn_mfma_f32_16x16x32_bf16(qh[mi][ks], kh[ni][ks], accs[mi][ni], 0, 0, 0);
          accs[mi][ni] = __builtin_amdgcn_mfma_f32_16x16x32_bf16(ql[mi][ks], kh[ni][ks], accs[mi][ni], 0, 0, 0);
        }
    __builtin_amdgcn_s_setprio(0);
    s16x8 vh[4][2], vl2[4][2];
    {
      const size_t vbase = (((size_t)(b * NHEAD + h)) * 64 + sr) * 1024 + kt + kg * 8;
#pragma unroll
      for (int nd = 0; nd < 4; ++nd)
#pragma unroll
        for (int ks2 = 0; ks2 < 2; ++ks2) {
          const size_t o = vbase + (size_t)nd * (16 * 1024) + ks2 * 32;
          vh[nd][ks2] = *(const s16x8*)(VTh + o);
          vl2[nd][ks2] = *(const s16x8*)(VTl + o);
        }
    }
#pragma unroll
    for (int mi = 0; mi < 2; ++mi)
#pragma unroll
      for (int r = 0; r < 4; ++r) {
        float mx = fmaxf(fmaxf(accs[mi][0][r], accs[mi][1][r]),
                         fmaxf(accs[mi][2][r], accs[mi][3][r]));
        mx = fmaxf(mx, __shfl_xor(mx, 1));
        mx = fmaxf(mx, __shfl_xor(mx, 2));
        mx = fmaxf(mx, __shfl_xor(mx, 4));
        mx = fmaxf(mx, __shfl_xor(mx, 8));
        const float mn = fmaxf(m_run[mi][r], mx);
        const float c = __expf(m_run[mi][r] - mn);
        m_run[mi][r] = mn;
        l_run[mi][r] *= c;
#pragma unroll
        for (int nd = 0; nd < 4; ++nd) acc_o[mi][nd][r] *= c;
        float sum = 0.f;
#pragma unroll
        for (int ni = 0; ni < 4; ++ni) {
          const float p = __expf(accs[mi][ni][r] - mn);
          const short hh = f2bf(p);
          sum += bf2f(hh);   // consistent with PV numerator (rounded P)
          const int idx = (mi * 2 + (ni >> 1)) * 640 + (rg * 4 + r) * 40 + (ni & 1) * 16 + cl;
          myPh[idx] = hh;
        }
        sum += __shfl_xor(sum, 1);
        sum += __shfl_xor(sum, 2);
        sum += __shfl_xor(sum, 4);
        sum += __shfl_xor(sum, 8);
        l_run[mi][r] += sum;
      }
    __builtin_amdgcn_s_setprio(1);
#pragma unroll
    for (int ks2 = 0; ks2 < 2; ++ks2) {
      s16x8 pf[2];
#pragma unroll
      for (int mi = 0; mi < 2; ++mi) {
        const int ra = (mi * 2 + ks2) * 640 + sr * 40 + kg * 8;
        pf[mi] = *(const s16x8*)&myPh[ra];
      }
#pragma unroll
      for (int nd = 0; nd < 4; ++nd)
#pragma unroll
        for (int mi = 0; mi < 2; ++mi) {
          acc_o[mi][nd] = __builtin_amdgcn_mfma_f32_16x16x32_bf16(pf[mi], vh[nd][ks2], acc_o[mi][nd], 0, 0, 0);
          acc_o[mi][nd] = __builtin_amdgcn_mfma_f32_16x16x32_bf16(pf[mi], vl2[nd][ks2], acc_o[mi][nd], 0, 0, 0);
        }
    }
    __builtin_amdgcn_s_setprio(0);
  }
#pragma unroll
  for (int mi = 0; mi < 2; ++mi)
#pragma unroll
    for (int nd = 0; nd < 4; ++nd)
#pragma unroll
      for (int r = 0; r < 4; ++r) {
        const int row = q0 + mi * 16 + rg * 4 + r;
        const int d = h * 64 + nd * 16 + cl;
        Op[((size_t)b * SEQ + row) * HDIM + d] = acc_o[mi][nd][r];
      }
  if (sr == 0) {
#pragma unroll
    for (int mi = 0; mi < 2; ++mi)
#pragma unroll
      for (int r = 0; r < 4; ++r) {
        const int row = q0 + mi * 16 + rg * 4 + r;
        mlp[(size_t)(b * NHEAD + h) * SEQ + row] = make_float2(m_run[mi][r], l_run[mi][r]);
      }
  }
}

// ============ combine two KV-half partials -> split-bf16 ctx (fused) ============
__global__ __launch_bounds__(256) void combine_split(
    const float* __restrict__ O0, const float* __restrict__ O1,
    const float2* __restrict__ ml0, const float2* __restrict__ ml1,
    short* __restrict__ Ch, short* __restrict__ Cl)
{
  const int t = blockIdx.x;
  const int b = t >> 10, s = t & 1023;
  const int tid = threadIdx.x;
#pragma unroll
  for (int i = 0; i < 3; ++i) {
    const int idx = tid + i * 256;
    const int h = idx >> 6;
    const float2 a0 = ml0[(size_t)(b * NHEAD + h) * SEQ + s];
    const float2 a1 = ml1[(size_t)(b * NHEAD + h) * SEQ + s];
    const float mm = fmaxf(a0.x, a1.x);
    const float w0 = __expf(a0.x - mm), w1 = __expf(a1.x - mm);
    const float denom = a0.y * w0 + a1.y * w1;
    const size_t o = (size_t)t * HDIM + idx;
    const float v = (O0[o] * w0 + O1[o] * w1) / denom;
    const short hh = f2bf(v);
    Ch[o] = hh;
    Cl[o] = f2bf(v - bf2f(hh));
  }
}

// ============ transpose + f32->bf16 (expert weights) ============
__global__ __launch_bounds__(256) void transpose_to_bf16(
    const float* __restrict__ W, short* __restrict__ WT, int K, int N)
{
  const size_t off = (size_t)blockIdx.z * (size_t)K * N;
  const float* Wp = W + off;
  short* WTp = WT + off;
  __shared__ float t[32][33];
  const int tid = threadIdx.x;
  const int tx = tid & 31, ty = tid >> 5;
  const int n0 = blockIdx.x * 32, k0 = blockIdx.y * 32;
#pragma unroll
  for (int r = 0; r < 4; ++r)
    t[ty + r * 8][tx] = Wp[(size_t)(k0 + ty + r * 8) * N + n0 + tx];
  __syncthreads();
#pragma unroll
  for (int r = 0; r < 4; ++r)
    WTp[(size_t)(n0 + ty + r * 8) * K + k0 + tx] = f2bf(t[tx][ty + r * 8]);
}

// ============ expert up-proj: depth-2 counted-vmcnt (32 KB LDS), compact grid ============
__global__ __launch_bounds__(256) void expert_up_mfma(
    const short* __restrict__ Abf, const short* __restrict__ WiT,
    const float* __restrict__ bi, const int* __restrict__ perm,
    const int* __restrict__ offs, short* __restrict__ interb)
{
  const int row0 = blockIdx.x * 128;
  if (row0 >= offs[NEXP]) return;
  int e = 0;
  while (offs[e + 1] <= row0) ++e;
  __shared__ __align__(16) short lA[2][4096];
  __shared__ __align__(16) short lB[2][4096];
  __shared__ int toks[128];
  const int tid = threadIdx.x;
  const int w = tid >> 6, lane = tid & 63;
  const int wr = w >> 1, wc = w & 1;
  const int col0 = blockIdx.y * 128;
  if (tid < 128) toks[tid] = perm[row0 + tid];   // pads already -1
  __syncthreads();
  const int sr = lane & 15, kg = lane >> 4;
  int t0 = toks[2 * w * 16 + sr];        if (t0 < 0) t0 = toks[0];
  int t1 = toks[(2 * w + 1) * 16 + sr];  if (t1 < 0) t1 = toks[0];
  const size_t a0 = (size_t)t0 * HDIM + kg * 8;
  const size_t a1 = (size_t)t1 * HDIM + kg * 8;
  const short* Bt = WiT + (size_t)e * FDIM * HDIM;
  const size_t b0 = (size_t)(col0 + 2 * w * 16 + sr) * HDIM + kg * 8;
  const size_t b1 = b0 + (size_t)16 * HDIM;
  const int d0 = (2 * w) * 512, d1 = (2 * w + 1) * 512;
#define STAGE_E(bu, k0) do { \
    gload16(Abf + a0 + (k0), &lA[bu][d0]); \
    gload16(Abf + a1 + (k0), &lA[bu][d1]); \
    gload16(Bt + b0 + (k0), &lB[bu][d0]); \
    gload16(Bt + b1 + (k0), &lB[bu][d1]); \
  } while (0)
  f32x4 acc[4][4] = {};
  STAGE_E(0, 0);
  STAGE_E(1, 32);
  asm volatile("s_waitcnt vmcnt(4)" ::: "memory");
  __builtin_amdgcn_s_barrier();
  for (int t = 0; t < 24; ++t) {
    const int cur = t & 1;
    s16x8 af[4], bg[4];
#pragma unroll
    for (int i = 0; i < 4; ++i) {
      af[i] = *(const s16x8*)&lA[cur][(wr * 4 + i) * 512 + lane * 8];
      bg[i] = *(const s16x8*)&lB[cur][(wc * 4 + i) * 512 + lane * 8];
    }
    lds_read_barrier();
    if (t + 2 < 24) STAGE_E(cur, (t + 2) * 32);
#pragma unroll
    for (int mi = 0; mi < 4; ++mi)
#pragma unroll
      for (int ni = 0; ni < 4; ++ni)
        acc[mi][ni] = __builtin_amdgcn_mfma_f32_16x16x32_bf16(af[mi], bg[ni], acc[mi][ni], 0, 0, 0);
    if (t + 2 < 24) asm volatile("s_waitcnt vmcnt(4)" ::: "memory");
    else            asm volatile("s_waitcnt vmcnt(0)" ::: "memory");
    __builtin_amdgcn_s_barrier();
  }
#undef STAGE_E
  const int cl = lane & 15, rg = lane >> 4;
#pragma unroll
  for (int mi = 0; mi < 4; ++mi) {
#pragma unroll
    for (int r = 0; r < 4; ++r) {
      const int rl = wr * 64 + mi * 16 + rg * 4 + r;
      const int tok = toks[rl];
      if (tok < 0) continue;
#pragma unroll
      for (int ni = 0; ni < 4; ++ni) {
        const int c = col0 + wc * 64 + ni * 16 + cl;
        float v = acc[mi][ni][r] + bi[(size_t)e * FDIM + c];
        v = 0.5f * v * (1.0f + erff(v * 0.70710678118654752f));
        interb[(size_t)tok * FDIM + c] = f2bf(v);
      }
    }
  }
}

// ============ down-proj: depth-2 counted-vmcnt (32 KB LDS), SPLIT-K x2 ============
__global__ __launch_bounds__(256) void wo_mfma(
    const short* __restrict__ Ab, const short* __restrict__ BT,
    const float* __restrict__ bias, float* __restrict__ C0, float* __restrict__ C1)
{
  __shared__ __align__(16) short lA[2][4096];
  __shared__ __align__(16) short lB[2][4096];
  const int tid = threadIdx.x;
  const int w = tid >> 6, lane = tid & 63;
  const int wr = w >> 1, wc = w & 1;
  const int row0 = blockIdx.y * 128, col0 = blockIdx.x * 128;
  const int z = blockIdx.z;
  const int kbase = z * 1536;
  const int sr = lane & 15, kg = lane >> 4;
  const size_t a0 = (size_t)(row0 + 2 * w * 16 + sr) * FDIM + kbase + kg * 8;
  const size_t a1 = a0 + (size_t)16 * FDIM;
  const size_t b0 = (size_t)(col0 + 2 * w * 16 + sr) * FDIM + kbase + kg * 8;
  const size_t b1 = b0 + (size_t)16 * FDIM;
  const int d0 = (2 * w) * 512, d1 = (2 * w + 1) * 512;
#define STAGE_W(bu, k0) do { \
    gload16(Ab + a0 + (k0), &lA[bu][d0]); \
    gload16(Ab + a1 + (k0), &lA[bu][d1]); \
    gload16(BT + b0 + (k0), &lB[bu][d0]); \
    gload16(BT + b1 + (k0), &lB[bu][d1]); \
  } while (0)
  f32x4 acc[4][4] = {};
  STAGE_W(0, 0);
  STAGE_W(1, 32);
  asm volatile("s_waitcnt vmcnt(4)" ::: "memory");
  __builtin_amdgcn_s_barrier();
  for (int t = 0; t < 48; ++t) {
    const int cur = t & 1;
    s16x8 af[4], bg[4];
#pragma unroll
    for (int i = 0; i < 4; ++i) {
      af[i] = *(const s16x8*)&lA[cur][(wr * 4 + i) * 512 + lane * 8];
      bg[i] = *(const s16x8*)&lB[cur][(wc * 4 + i) * 512 + lane * 8];
    }
    lds_read_barrier();
    if (t + 2 < 48) STAGE_W(cur, (t + 2) * 32);
#pragma unroll
    for (int mi = 0; mi < 4; ++mi)
#pragma unroll
      for (int ni = 0; ni < 4; ++ni)
        acc[mi][ni] = __builtin_amdgcn_mfma_f32_16x16x32_bf16(af[mi], bg[ni], acc[mi][ni], 0, 0, 0);
    if (t + 2 < 48) asm volatile("s_waitcnt vmcnt(4)" ::: "memory");
    else            asm volatile("s_waitcnt vmcnt(0)" ::: "memory");
    __builtin_amdgcn_s_barrier();
  }
#undef STAGE_W
  float* C = z ? C1 : C0;
  const int cl = lane & 15, rg = lane >> 4;
#pragma unroll
  for (int mi = 0; mi < 4; ++mi) {
#pragma unroll
    for (int r = 0; r < 4; ++r) {
      const int row = row0 + wr * 64 + mi * 16 + rg * 4 + r;
#pragma unroll
      for (int ni = 0; ni < 4; ++ni) {
        const int c = col0 + wc * 64 + ni * 16 + cl;
        C[(size_t)row * HDIM + c] = acc[mi][ni][r] + (z ? 0.f : bias[c]);
      }
    }
  }
}

// ============ two-partial add + residual + LayerNorm ============
__global__ __launch_bounds__(256) void add2_ln_kernel(
    const float* __restrict__ X1, const float* __restrict__ X2,
    const float* __restrict__ R, const float* __restrict__ g,
    const float* __restrict__ bb, float* __restrict__ out)
{
  const int t = blockIdx.x;
  const int tid = threadIdx.x;
  const float* x1 = X1 + (size_t)t * HDIM;
  const float* x2 = X2 + (size_t)t * HDIM;
  const float* r = R + (size_t)t * HDIM;
  float v[3];
  float sum = 0.f, ssq = 0.f;
#pragma unroll
  for (int i = 0; i < 3; ++i) {
    const float val = x1[tid + i * 256] + x2[tid + i * 256] + r[tid + i * 256];
    v[i] = val;
    sum += val;
    ssq += val * val;
  }
#pragma unroll
  for (int o = 32; o > 0; o >>= 1) {
    sum += __shfl_down(sum, o);
    ssq += __shfl_down(ssq, o);
  }
  __shared__ float red[10];
  const int wid = tid >> 6, lane = tid & 63;
  if (lane == 0) { red[wid] = sum; red[4 + wid] = ssq; }
  __syncthreads();
  if (tid == 0) {
    const float s = red[0] + red[1] + red[2] + red[3];
    const float q = red[4] + red[5] + red[6] + red[7];
    const float mean = s * (1.f / HDIM);
    const float var = q * (1.f / HDIM) - mean * mean;
    red[8] = mean;
    red[9] = rsqrtf(fmaxf(var, 0.f) + 1e-12f);
  }
  __syncthreads();
  const float mean = red[8], rstd = red[9];
#pragma unroll
  for (int i = 0; i < 3; ++i) {
    const int idx = tid + i * 256;
    out[(size_t)t * HDIM + idx] = g[idx] * (v[i] - mean) * rstd + bb[idx];
  }
}

// ============ LN1 variant: also emits bf16 copy (fuses convert_bf16) ============
__global__ __launch_bounds__(256) void add2_ln_bf16_kernel(
    const float* __restrict__ X1, const float* __restrict__ X2,
    const float* __restrict__ R, const float* __restrict__ g,
    const float* __restrict__ bb, float* __restrict__ out, short* __restrict__ outb)
{
  const int t = blockIdx.x;
  const int tid = threadIdx.x;
  const float* x1 = X1 + (size_t)t * HDIM;
  const float* x2 = X2 + (size_t)t * HDIM;
  const float* r = R + (size_t)t * HDIM;
  float v[3];
  float sum = 0.f, ssq = 0.f;
#pragma unroll
  for (int i = 0; i < 3; ++i) {
    const float val = x1[tid + i * 256] + x2[tid + i * 256] + r[tid + i * 256];
    v[i] = val;
    sum += val;
    ssq += val * val;
  }
#pragma unroll
  for (int o = 32; o > 0; o >>= 1) {
    sum += __shfl_down(sum, o);
    ssq += __shfl_down(ssq, o);
  }
  __shared__ float red[10];
  const int wid = tid >> 6, lane = tid & 63;
  if (lane == 0) { red[wid] = sum; red[4 + wid] = ssq; }
  __syncthreads();
  if (tid == 0) {
    const float s = red[0] + red[1] + red[2] + red[3];
    const float q = red[4] + red[5] + red[6] + red[7];
    const float mean = s * (1.f / HDIM);
    const float var = q * (1.f / HDIM) - mean * mean;
    red[8] = mean;
    red[9] = rsqrtf(fmaxf(var, 0.f) + 1e-12f);
  }
  __syncthreads();
  const float mean = red[8], rstd = red[9];
#pragma unroll
  for (int i = 0; i < 3; ++i) {
    const int idx = tid + i * 256;
    const float o = g[idx] * (v[i] - mean) * rstd + bb[idx];
    out[(size_t)t * HDIM + idx] = o;
    outb[(size_t)t * HDIM + idx] = f2bf(o);
  }
}

// ============ router (f32 — keeps argmax path bit-identical) ============
__global__ __launch_bounds__(256) void router_kernel(
    const float* __restrict__ X, const float* __restrict__ Wr,
    const float* __restrict__ br, float* __restrict__ scores_out,
    int* __restrict__ expert, int* __restrict__ counts)
{
  const int wid = threadIdx.x >> 6, lane = threadIdx.x & 63;
  const int tok = blockIdx.x * 4 + wid;
  const float* x = X + (size_t)tok * HDIM;
  float acc[8] = {};
  for (int k0 = 0; k0 < HDIM; k0 += 64) {
    const float xv = x[k0 + lane];
    const float* wrow = Wr + (size_t)(k0 + lane) * NEXP;
    const float4 w0 = *reinterpret_cast<const float4*>(wrow);
    const float4 w1 = *reinterpret_cast<const float4*>(wrow + 4);
    acc[0] = fmaf(xv, w0.x, acc[0]);
    acc[1] = fmaf(xv, w0.y, acc[1]);
    acc[2] = fmaf(xv, w0.z, acc[2]);
    acc[3] = fmaf(xv, w0.w, acc[3]);
    acc[4] = fmaf(xv, w1.x, acc[4]);
    acc[5] = fmaf(xv, w1.y, acc[5]);
    acc[6] = fmaf(xv, w1.z, acc[6]);
    acc[7] = fmaf(xv, w1.w, acc[7]);
  }
#pragma unroll
  for (int e = 0; e < 8; ++e)
#pragma unroll
    for (int o = 32; o > 0; o >>= 1) acc[e] += __shfl_down(acc[e], o);
  if (lane == 0) {
    float mx = -3.0e38f;
#pragma unroll
    for (int e = 0; e < 8; ++e) { acc[e] += br[e]; mx = fmaxf(mx, acc[e]); }
    float sum = 0.f;
#pragma unroll
    for (int e = 0; e < 8; ++e) { acc[e] = expf(acc[e] - mx); sum += acc[e]; }
    const float inv = 1.f / sum;
    int best = 0;
    float bv = acc[0];
#pragma unroll
    for (int e = 0; e < 8; ++e) {
      const float p = acc[e] * inv;
      scores_out[(size_t)tok * NEXP + e] = p;
      if (acc[e] > bv) { bv = acc[e]; best = e; }
    }
    expert[tok] = best;
    atomicAdd(&counts[best], 1);
  }
}

// padded prefix: each expert segment rounded up to a multiple of 128
__global__ void offsets_kernel(const int* __restrict__ counts, int* __restrict__ offs)
{
  if (threadIdx.x == 0 && blockIdx.x == 0) {
    int a = 0;
    for (int e = 0; e < NEXP; ++e) {
      offs[e] = a;
      a += ((counts[e] + 127) >> 7) << 7;
    }
    offs[NEXP] = a;
  }
}

__global__ __launch_bounds__(256) void scatter_kernel(
    const int* __restrict__ expert, const int* __restrict__ offs,
    int* __restrict__ cursor, int* __restrict__ perm)
{
  const int t = blockIdx.x * 256 + threadIdx.x;
  if (t >= TOKS) return;
  const int e = expert[t];
  const int pos = atomicAdd(&cursor[e], 1);
  perm[offs[e] + pos] = t;
}

extern "C" void kernel_launch(void* const* d_in, const int* in_sizes, int n_in,
                              void* d_out, int out_size, void* d_ws, size_t ws_size,
                              hipStream_t stream) {
  const float* hidden = (const float*)d_in[0];
  const float* Wq  = (const float*)d_in[1];
  const float* bq  = (const float*)d_in[2];
  const float* Wk  = (const float*)d_in[3];
  const float* bk  = (const float*)d_in[4];
  const float* Wv  = (const float*)d_in[5];
  const float* bv  = (const float*)d_in[6];
  const float* Wao = (const float*)d_in[7];
  const float* bao = (const float*)d_in[8];
  const float* ln1g = (const float*)d_in[9];
  const float* ln1b = (const float*)d_in[10];
  const float* Wr  = (const float*)d_in[11];
  const float* br  = (const float*)d_in[12];
  const float* Wi  = (const float*)d_in[13];
  const float* bi  = (const float*)d_in[14];
  const float* Wo  = (const float*)d_in[15];
  const float* bo  = (const float*)d_in[16];
  const float* ln2g = (const float*)d_in[17];
  const float* ln2b = (const float*)d_in[18];

  float* out = (float*)d_out;
  float* scores_out = out + (size_t)TOKS * HDIM;

  const size_t M1 = (size_t)TOKS * HDIM;     // 6.29M floats
  const size_t HW = (size_t)HDIM * HDIM;
  float* ws = (float*)d_ws;
  // ---- arena (float offsets, by liveness) ----
  short* QKhb = (short*)ws;
  short* QKlb = (short*)(ws + M1);
  short* VThb = (short*)(ws + 2 * M1);
  short* VTlb = VThb + (size_t)BATCH * NHEAD * 64 * 1024;
  float* O0b  = ws + 3 * M1;
  float* O1b  = ws + 4 * M1;
  float* bqkv = ws + 3 * M1;                 // dead before attention writes O0
  short* Hh = (short*)(ws + 4 * M1);
  short* Hl = Hh + M1;
  short* Ch = (short*)(ws + 2 * M1);         // ctx split (VT region, dead after attention)
  short* Cl = Ch + M1;
  short* wt = (short*)(ws + 5 * M1);
  short* WqkvhT = wt;
  short* WqkvlT = wt + 3 * HW;
  short* WaohT  = wt + 6 * HW;
  short* WaolT  = wt + 7 * HW;
  float2* ml0 = (float2*)(ws + 5 * M1 + 4 * HW);
  float2* ml1 = ml0 + (size_t)BATCH * NHEAD * SEQ;
  float* aoproj0  = ws;                      // QKhb region (dead after attention)
  float* aoproj1  = ws + 3 * M1;             // O0 region (dead after combine)
  float* attn_out = ws + M1;                 // QKlb region
  float* tmp2a    = ws;
  float* tmp2b    = ws + 3 * M1;
  short* Abf    = (short*)(ws + 2 * M1);     // expert phase (Ch/Cl dead after AO)
  short* WiT    = Abf + M1;
  short* WoT    = WiT + (size_t)NEXP * FDIM * HDIM;
  short* interb = WoT + (size_t)HDIM * FDIM;
  int* ints   = (int*)(interb + (size_t)TOKS * FDIM);
  int* perm   = ints;                        // PERMSZ (padded)
  int* expert = ints + PERMSZ;
  int* counts = expert + TOKS;
  int* offs   = counts + NEXP;               // NEXP+1 padded prefix
  int* cursor = offs + NEXP + 1;

  hipMemsetAsync(counts, 0, (NEXP + NEXP + 1 + NEXP) * sizeof(int), stream);
  hipMemsetAsync(perm, 0xFF, PERMSZ * sizeof(int), stream);   // pads = -1
  hipMemcpyAsync(bqkv,        bq, HDIM * sizeof(float), hipMemcpyDeviceToDevice, stream);
  hipMemcpyAsync(bqkv + 768,  bk, HDIM * sizeof(float), hipMemcpyDeviceToDevice, stream);
  hipMemcpyAsync(bqkv + 1536, bv, HDIM * sizeof(float), hipMemcpyDeviceToDevice, stream);

  const dim3 blk(256);
  // --- split prep ---
  convert_split<<<dim3(TOKS * HDIM / 4 / 256), blk, 0, stream>>>(hidden, Hh, Hl, TOKS * HDIM / 4);
  transpose_split<<<dim3(24, 24), blk, 0, stream>>>(Wq,  WqkvhT,          WqkvlT,          HDIM, HDIM);
  transpose_split<<<dim3(24, 24), blk, 0, stream>>>(Wk,  WqkvhT + HW,     WqkvlT + HW,     HDIM, HDIM);
  transpose_split<<<dim3(24, 24), blk, 0, stream>>>(Wv,  WqkvhT + 2 * HW, WqkvlT + 2 * HW, HDIM, HDIM);
  transpose_split<<<dim3(24, 24), blk, 0, stream>>>(Wao, WaohT,           WaolT,           HDIM, HDIM);

  // --- fused QKV projection (depth-2 counted-vmcnt pipeline + XCD swizzle) ---
  qkv_split_mfma<<<dim3(2304 / 128, TOKS / 128), blk, 0, stream>>>(
      Hh, Hl, WqkvhT, WqkvlT, bqkv, QKhb, QKlb, VThb, VTlb);

  // --- MFMA flash attention (bf16 P, Kh-only QK), KV-split x2, 2-wave blocks ---
  attention_part<<<dim3((SEQ / 64) * 2, NHEAD, BATCH), dim3(128), 0, stream>>>(
      QKhb, QKlb, VThb, VTlb, O0b, O1b, ml0, ml1);
  combine_split<<<dim3(TOKS), blk, 0, stream>>>(O0b, O1b, ml0, ml1, Ch, Cl);

  // --- AO projection (depth-2 pipeline, split-K x2) + LN1 (fused bf16 emit -> Abf) ---
  gemm_splitk_staged<<<dim3(HDIM / 128, TOKS / 128, 2), blk, 0, stream>>>(
      Ch, Cl, WaohT, WaolT, bao, aoproj0, aoproj1, HDIM, HDIM);
  add2_ln_bf16_kernel<<<dim3(TOKS), blk, 0, stream>>>(
      aoproj0, aoproj1, hidden, ln1g, ln1b, attn_out, Abf);

  // --- router + dispatch (padded permutation) ---
  router_kernel<<<dim3(TOKS / 4), blk, 0, stream>>>(attn_out, Wr, br, scores_out, expert, counts);
  offsets_kernel<<<dim3(1), dim3(64), 0, stream>>>(counts, offs);
  scatter_kernel<<<dim3(TOKS / 256), blk, 0, stream>>>(expert, offs, cursor, perm);

  // --- expert FFN (depth-2 pipelines; split-K down-proj) ---
  transpose_to_bf16<<<dim3(FDIM / 32, HDIM / 32, NEXP), blk, 0, stream>>>(Wi, WiT, HDIM, FDIM);
  transpose_to_bf16<<<dim3(HDIM / 32, FDIM / 32, 1), blk, 0, stream>>>(Wo, WoT, FDIM, HDIM);

  expert_up_mfma<<<dim3(PERMSZ / 128, FDIM / 128), blk, 0, stream>>>(
      Abf, WiT, bi, perm, offs, interb);
  wo_mfma<<<dim3(HDIM / 128, TOKS / 128, 2), blk, 0, stream>>>(interb, WoT, bo, tmp2a, tmp2b);
  add2_ln_kernel<<<dim3(TOKS), blk, 0, stream>>>(tmp2a, tmp2b, attn_out, ln2g, ln2b, out);
}

// Round 25
// 804.340 us; speedup vs baseline: 1.0346x; 1.0346x over previous
//
#include <hip/hip_runtime.h>
#include <math.h>
#include <stdint.h>

#define TOKS 8192
#define HDIM 768
#define FDIM 3072
#define NEXP 8
#define NHEAD 12
#define SEQ 1024
#define BATCH 8
#define PERMSZ 9216   // 8192 + 8*128 worst-case padding

typedef __attribute__((ext_vector_type(8))) short s16x8;   // 8 bf16 = 4 VGPR
typedef __attribute__((ext_vector_type(4))) short s16x4;
typedef __attribute__((ext_vector_type(4))) float f32x4;

__device__ __forceinline__ short f2bf(float f) {
  uint32_t u = __float_as_uint(f);
  uint32_t r = (u + 0x7fffu + ((u >> 16) & 1u)) >> 16;   // RTN-even
  return (short)(r & 0xffffu);
}
__device__ __forceinline__ float bf2f(short h) {
  return __uint_as_float(((uint32_t)(uint16_t)h) << 16);
}
__device__ __forceinline__ void gload16(const void* g, void* l) {
  __builtin_amdgcn_global_load_lds(
      (const __attribute__((address_space(1))) uint32_t*)g,
      (__attribute__((address_space(3))) uint32_t*)l, 16, 0, 0);
}
// drain outstanding global->LDS DMA, then workgroup barrier.
__device__ __forceinline__ void pipe_wait_barrier() {
  asm volatile("s_waitcnt vmcnt(0)" ::: "memory");
  __builtin_amdgcn_s_barrier();
}
// LDS-reads-retired fence + raw barrier (no vmcnt drain — keeps DMA in flight).
__device__ __forceinline__ void lds_read_barrier() {
  asm volatile("s_waitcnt lgkmcnt(0)" ::: "memory");
  __builtin_amdgcn_s_barrier();
}

// ============ f32 -> (hi,lo) bf16 split, 4 elems/thread ============
__global__ __launch_bounds__(256) void convert_split(
    const float* __restrict__ X, short* __restrict__ Xh, short* __restrict__ Xl, int n4)
{
  const int i = blockIdx.x * 256 + threadIdx.x;
  if (i >= n4) return;
  const float4 v = ((const float4*)X)[i];
  const float a[4] = {v.x, v.y, v.z, v.w};
  s16x4 h, l;
#pragma unroll
  for (int j = 0; j < 4; ++j) {
    h[j] = f2bf(a[j]);
    l[j] = f2bf(a[j] - bf2f(h[j]));
  }
  ((s16x4*)Xh)[i] = h;
  ((s16x4*)Xl)[i] = l;
}

// ============ transpose + split: WT{h,l}[n][k] = split(W[k][n]) ============
__global__ __launch_bounds__(256) void transpose_split(
    const float* __restrict__ W, short* __restrict__ WTh, short* __restrict__ WTl,
    int K, int N)
{
  __shared__ float t[32][33];
  const int tid = threadIdx.x;
  const int tx = tid & 31, ty = tid >> 5;
  const int n0 = blockIdx.x * 32, k0 = blockIdx.y * 32;
#pragma unroll
  for (int r = 0; r < 4; ++r)
    t[ty + r * 8][tx] = W[(size_t)(k0 + ty + r * 8) * N + n0 + tx];
  __syncthreads();
#pragma unroll
  for (int r = 0; r < 4; ++r) {
    const float v = t[tx][ty + r * 8];
    const short h = f2bf(v);
    WTh[(size_t)(n0 + ty + r * 8) * K + k0 + tx] = h;
    WTl[(size_t)(n0 + ty + r * 8) * K + k0 + tx] = f2bf(v - bf2f(h));
  }
}

// ============ QKV split-GEMM: depth-2 counted-vmcnt pipeline (64 KB LDS),
// raw barriers (no vmcnt drain mid-loop); XCD-swizzled grid; Q pre-scaled 1/8.
// (KEPT from R24: 182->162 us. Long 24-step loop + residency-insensitive.) ====
__global__ __launch_bounds__(256) void qkv_split_mfma(
    const short* __restrict__ Ah, const short* __restrict__ Al,
    const short* __restrict__ BhT, const short* __restrict__ BlT,
    const float* __restrict__ bias,
    short* __restrict__ QKh, short* __restrict__ QKl,
    short* __restrict__ VTh, short* __restrict__ VTl)
{
  const int K = 768;
  __shared__ __align__(16) short lAh[2][4096];
  __shared__ __align__(16) short lAl[2][4096];
  __shared__ __align__(16) short lBh[2][4096];
  __shared__ __align__(16) short lBl[2][4096];
  // XCD swizzle: nwg = 18*64 = 1152, chunk = 144 per XCD (bijective)
  const int dsp = blockIdx.x + 18 * blockIdx.y;
  const int orig = (dsp & 7) * 144 + (dsp >> 3);
  const int bx = orig % 18, by = orig / 18;
  const int tid = threadIdx.x;
  const int w = tid >> 6, lane = tid & 63;
  const int wr = w >> 1, wc = w & 1;
  const int row0 = by * 128, col0 = bx * 128;
  const int sr = lane & 15, kg = lane >> 4;
  const size_t a0 = (size_t)(row0 + 2 * w * 16 + sr) * K + kg * 8;
  const size_t a1 = a0 + (size_t)16 * K;
  const size_t b0 = (size_t)(col0 + 2 * w * 16 + sr) * K + kg * 8;
  const size_t b1 = b0 + (size_t)16 * K;
  const int d0 = (2 * w) * 512, d1 = (2 * w + 1) * 512;
#define STAGE_Q(bu, k0) do { \
    gload16(Ah + a0 + (k0), &lAh[bu][d0]); \
    gload16(Ah + a1 + (k0), &lAh[bu][d1]); \
    gload16(Al + a0 + (k0), &lAl[bu][d0]); \
    gload16(Al + a1 + (k0), &lAl[bu][d1]); \
    gload16(BhT + b0 + (k0), &lBh[bu][d0]); \
    gload16(BhT + b1 + (k0), &lBh[bu][d1]); \
    gload16(BlT + b0 + (k0), &lBl[bu][d0]); \
    gload16(BlT + b1 + (k0), &lBl[bu][d1]); \
  } while (0)
  f32x4 acc[4][4] = {};
  STAGE_Q(0, 0);
  STAGE_Q(1, 32);
  asm volatile("s_waitcnt vmcnt(8)" ::: "memory");   // stage(0) landed; stage(1) in flight
  __builtin_amdgcn_s_barrier();
  for (int t = 0; t < 24; ++t) {
    const int cur = t & 1;
    s16x8 ah[4], al[4], bh[4], bl[4];
#pragma unroll
    for (int i = 0; i < 4; ++i) {
      ah[i] = *(const s16x8*)&lAh[cur][(wr * 4 + i) * 512 + lane * 8];
      al[i] = *(const s16x8*)&lAl[cur][(wr * 4 + i) * 512 + lane * 8];
      bh[i] = *(const s16x8*)&lBh[cur][(wc * 4 + i) * 512 + lane * 8];
      bl[i] = *(const s16x8*)&lBl[cur][(wc * 4 + i) * 512 + lane * 8];
    }
    lds_read_barrier();   // reads retired; buf[cur] free (DMA stays in flight!)
    if (t + 2 < 24) STAGE_Q(cur, (t + 2) * 32);   // depth-2 prefetch into freed buffer
#pragma unroll
    for (int mi = 0; mi < 4; ++mi)
#pragma unroll
      for (int ni = 0; ni < 4; ++ni) {
        acc[mi][ni] = __builtin_amdgcn_mfma_f32_16x16x32_bf16(ah[mi], bh[ni], acc[mi][ni], 0, 0, 0);
        acc[mi][ni] = __builtin_amdgcn_mfma_f32_16x16x32_bf16(ah[mi], bl[ni], acc[mi][ni], 0, 0, 0);
        acc[mi][ni] = __builtin_amdgcn_mfma_f32_16x16x32_bf16(al[mi], bh[ni], acc[mi][ni], 0, 0, 0);
      }
    // counted wait: stage(t+1) done, stage(t+2)'s 8 loads remain outstanding
    if (t + 2 < 24) asm volatile("s_waitcnt vmcnt(8)" ::: "memory");
    else            asm volatile("s_waitcnt vmcnt(0)" ::: "memory");
    __builtin_amdgcn_s_barrier();
  }
#undef STAGE_Q
  const int cl = lane & 15, rg = lane >> 4;
#pragma unroll
  for (int mi = 0; mi < 4; ++mi)
#pragma unroll
    for (int ni = 0; ni < 4; ++ni) {
      const int c = col0 + wc * 64 + ni * 16 + cl;
      const int rowb = row0 + wr * 64 + mi * 16 + rg * 4;
      // Q columns (c<768) pre-scaled by 1/8: exact power-of-2, commutes through
      // the bf16 split and the QK^T MFMA bit-exactly.
      const float qscale = (c < 768) ? 0.125f : 1.0f;
      s16x4 hv, lv;
#pragma unroll
      for (int r = 0; r < 4; ++r) {
        const float v = (acc[mi][ni][r] + bias[c]) * qscale;
        const short hh = f2bf(v);
        hv[r] = hh;
        lv[r] = f2bf(v - bf2f(hh));
      }
      if (c < 1536) {
#pragma unroll
        for (int r = 0; r < 4; ++r) {
          QKh[(size_t)(rowb + r) * 1536 + c] = hv[r];
          QKl[(size_t)(rowb + r) * 1536 + c] = lv[r];
        }
      } else {          // V column: transposed store VT[b][h][d][s]
        const int dall = c - 1536;
        const size_t vi = (((size_t)((rowb >> 10) * NHEAD + (dall >> 6))) * 64 + (dall & 63)) * 1024
                          + (rowb & 1023);
        *(s16x4*)(VTh + vi) = hv;
        *(s16x4*)(VTl + vi) = lv;
      }
    }
}

// ============ AO GEMM: single-buffer split-bf16 (32 KB LDS), SPLIT-K x2
// (REVERTED to R23: NT=12 too short for depth-2; 64KB halved occupancy 5->2) ====
__global__ __launch_bounds__(256) void gemm_splitk_staged(
    const short* __restrict__ Ah, const short* __restrict__ Al,
    const short* __restrict__ BhT, const short* __restrict__ BlT,
    const float* __restrict__ bias, float* __restrict__ C0, float* __restrict__ C1,
    int N, int K)
{
  __shared__ __align__(16) short lAh[4096];
  __shared__ __align__(16) short lAl[4096];
  __shared__ __align__(16) short lBh[4096];
  __shared__ __align__(16) short lBl[4096];
  const int tid = threadIdx.x;
  const int w = tid >> 6, lane = tid & 63;
  const int wr = w >> 1, wc = w & 1;
  const int row0 = blockIdx.y * 128, col0 = blockIdx.x * 128;
  const int z = blockIdx.z;
  const int Khalf = K >> 1, koff = z * Khalf;
  const int sr = lane & 15, kg = lane >> 4;
  const size_t a0 = (size_t)(row0 + 2 * w * 16 + sr) * K + koff + kg * 8;
  const size_t a1 = a0 + (size_t)16 * K;
  const size_t b0 = (size_t)(col0 + 2 * w * 16 + sr) * K + koff + kg * 8;
  const size_t b1 = b0 + (size_t)16 * K;
  const int d0 = (2 * w) * 512, d1 = (2 * w + 1) * 512;
#define STAGE_K4(k0) do { \
    gload16(Ah + a0 + (k0), &lAh[d0]); \
    gload16(Ah + a1 + (k0), &lAh[d1]); \
    gload16(Al + a0 + (k0), &lAl[d0]); \
    gload16(Al + a1 + (k0), &lAl[d1]); \
    gload16(BhT + b0 + (k0), &lBh[d0]); \
    gload16(BhT + b1 + (k0), &lBh[d1]); \
    gload16(BlT + b0 + (k0), &lBl[d0]); \
    gload16(BlT + b1 + (k0), &lBl[d1]); \
  } while (0)
  f32x4 acc[4][4] = {};
  const int NT = Khalf >> 5;
  STAGE_K4(0);
  pipe_wait_barrier();
  for (int t = 0; t < NT; ++t) {
    s16x8 ah[4], al[4], bh[4], bl[4];
#pragma unroll
    for (int i = 0; i < 4; ++i) {
      ah[i] = *(const s16x8*)&lAh[(wr * 4 + i) * 512 + lane * 8];
      al[i] = *(const s16x8*)&lAl[(wr * 4 + i) * 512 + lane * 8];
      bh[i] = *(const s16x8*)&lBh[(wc * 4 + i) * 512 + lane * 8];
      bl[i] = *(const s16x8*)&lBl[(wc * 4 + i) * 512 + lane * 8];
    }
    __syncthreads();
    if (t + 1 < NT) STAGE_K4((t + 1) * 32);
#pragma unroll
    for (int mi = 0; mi < 4; ++mi)
#pragma unroll
      for (int ni = 0; ni < 4; ++ni) {
        acc[mi][ni] = __builtin_amdgcn_mfma_f32_16x16x32_bf16(ah[mi], bh[ni], acc[mi][ni], 0, 0, 0);
        acc[mi][ni] = __builtin_amdgcn_mfma_f32_16x16x32_bf16(ah[mi], bl[ni], acc[mi][ni], 0, 0, 0);
        acc[mi][ni] = __builtin_amdgcn_mfma_f32_16x16x32_bf16(al[mi], bh[ni], acc[mi][ni], 0, 0, 0);
      }
    pipe_wait_barrier();
  }
#undef STAGE_K4
  float* C = z ? C1 : C0;
  const int cl = lane & 15, rg = lane >> 4;
#pragma unroll
  for (int mi = 0; mi < 4; ++mi)
#pragma unroll
    for (int r = 0; r < 4; ++r) {
      const int row = row0 + wr * 64 + mi * 16 + rg * 4 + r;
#pragma unroll
      for (int ni = 0; ni < 4; ++ni) {
        const int c = col0 + wc * 64 + ni * 16 + cl;
        C[(size_t)row * N + c] = acc[mi][ni][r] + (z ? 0.f : bias[c]);
      }
    }
}

// ============ MFMA flash attention, KV-SPLIT x2 — TWO-WAVE blocks (10 KB LDS) ============
// P plain bf16; QK^T uses (Qh+Ql)*Kh only (Kl dropped: S err ~3e-3 abs, averaged to
// ~1e-4 in O by softmax over ~900 keys — router-safe class, same as bf16-P change).
__global__ __launch_bounds__(128, 2) void attention_part(
    const short* __restrict__ QKh, const short* __restrict__ QKl,
    const short* __restrict__ VTh, const short* __restrict__ VTl,
    float* __restrict__ O0, float* __restrict__ O1,
    float2* __restrict__ ml0, float2* __restrict__ ml1)
{
  __shared__ __align__(16) short lPh[2][2560];   // [wave][(mi*2+ks2)*640 + q*40 + koff]
  const int tid = threadIdx.x;
  const int w = tid >> 6, lane = tid & 63;
  // XCD swizzle: nwg = 32*12*8 = 3072, chunk = 384 (= one batch per XCD)
  const int dsp = blockIdx.x + 32 * (blockIdx.y + 12 * blockIdx.z);
  const int orig = (dsp & 7) * 384 + (dsp >> 3);
  const int wx = orig & 31;
  const int b = orig / 384, h = (orig >> 5) % 12;
  const int z = wx & 1;
  const int q0 = (wx >> 1) * 64 + w * 32;    // this wave's 32 q-rows
  const int kv0 = z * 512;
  const int sr = lane & 15, kg = lane >> 4;
  const int cl = sr, rg = kg;
  short* myPh = lPh[w];
  float* Op = z ? O1 : O0;
  float2* mlp = z ? ml1 : ml0;

  s16x8 qh[2][2], ql[2][2];
  {
    const size_t qbase = ((size_t)b * SEQ + q0 + sr) * 1536 + h * 64 + kg * 8;
#pragma unroll
    for (int mi = 0; mi < 2; ++mi)
#pragma unroll
      for (int ks = 0; ks < 2; ++ks) {
        const size_t o = qbase + (size_t)mi * (16 * 1536) + ks * 32;
        qh[mi][ks] = *(const s16x8*)(QKh + o);
        ql[mi][ks] = *(const s16x8*)(QKl + o);
      }
  }
  float m_run[2][4], l_run[2][4];
#pragma unroll
  for (int mi = 0; mi < 2; ++mi)
#pragma unroll
    for (int r = 0; r < 4; ++r) { m_run[mi][r] = -3.0e38f; l_run[mi][r] = 0.f; }
  f32x4 acc_o[2][4] = {};

  for (int kt = kv0; kt < kv0 + 512; kt += 64) {
    s16x8 kh[4][2];
    {
      const size_t kbase = ((size_t)b * SEQ + kt + sr) * 1536 + 768 + h * 64 + kg * 8;
#pragma unroll
      for (int ni = 0; ni < 4; ++ni)
#pragma unroll
        for (int ks = 0; ks < 2; ++ks) {
          const size_t o = kbase + (size_t)ni * (16 * 1536) + ks * 32;
          kh[ni][ks] = *(const s16x8*)(QKh + o);
        }
    }
    f32x4 accs[2][4] = {};
    __builtin_amdgcn_s_setprio(1);
#pragma unroll
    for (int ks = 0; ks < 2; ++ks)
#pragma unroll
      for (int ni = 0; ni < 4; ++ni)
#pragma unroll
        for (int mi = 0; mi < 2; ++mi) {
          accs[mi][ni] = __builtin_amdgcn_mfma_f32_16x16x32_bf16(qh[mi][ks], kh[ni][ks], accs[mi][ni], 0, 0, 0);
          accs[mi][ni] = __builtin_amdgcn_mfma_f32_16x16x32_bf16(ql[mi][ks], kh[ni][ks], accs[mi][ni], 0, 0, 0);
        }
    __builtin_amdgcn_s_setprio(0);
    s16x8 vh[4][2], vl2[4][2];
    {
      const size_t vbase = (((size_t)(b * NHEAD + h)) * 64 + sr) * 1024 + kt + kg * 8;
#pragma unroll
      for (int nd = 0; nd < 4; ++nd)
#pragma unroll
        for (int ks2 = 0; ks2 < 2; ++ks2) {
          const size_t o = vbase + (size_t)nd * (16 * 1024) + ks2 * 32;
          vh[nd][ks2] = *(const s16x8*)(VTh + o);
          vl2[nd][ks2] = *(const s16x8*)(VTl + o);
        }
    }
#pragma unroll
    for (int mi = 0; mi < 2; ++mi)
#pragma unroll
      for (int r = 0; r < 4; ++r) {
        float mx = fmaxf(fmaxf(accs[mi][0][r], accs[mi][1][r]),
                         fmaxf(accs[mi][2][r], accs[mi][3][r]));
        mx = fmaxf(mx, __shfl_xor(mx, 1));
        mx = fmaxf(mx, __shfl_xor(mx, 2));
        mx = fmaxf(mx, __shfl_xor(mx, 4));
        mx = fmaxf(mx, __shfl_xor(mx, 8));
        const float mn = fmaxf(m_run[mi][r], mx);
        const float c = __expf(m_run[mi][r] - mn);
        m_run[mi][r] = mn;
        l_run[mi][r] *= c;
#pragma unroll
        for (int nd = 0; nd < 4; ++nd) acc_o[mi][nd][r] *= c;
        float sum = 0.f;
#pragma unroll
        for (int ni = 0; ni < 4; ++ni) {
          const float p = __expf(accs[mi][ni][r] - mn);
          const short hh = f2bf(p);
          sum += bf2f(hh);   // consistent with PV numerator (rounded P)
          const int idx = (mi * 2 + (ni >> 1)) * 640 + (rg * 4 + r) * 40 + (ni & 1) * 16 + cl;
          myPh[idx] = hh;
        }
        sum += __shfl_xor(sum, 1);
        sum += __shfl_xor(sum, 2);
        sum += __shfl_xor(sum, 4);
        sum += __shfl_xor(sum, 8);
        l_run[mi][r] += sum;
      }
    __builtin_amdgcn_s_setprio(1);
#pragma unroll
    for (int ks2 = 0; ks2 < 2; ++ks2) {
      s16x8 pf[2];
#pragma unroll
      for (int mi = 0; mi < 2; ++mi) {
        const int ra = (mi * 2 + ks2) * 640 + sr * 40 + kg * 8;
        pf[mi] = *(const s16x8*)&myPh[ra];
      }
#pragma unroll
      for (int nd = 0; nd < 4; ++nd)
#pragma unroll
        for (int mi = 0; mi < 2; ++mi) {
          acc_o[mi][nd] = __builtin_amdgcn_mfma_f32_16x16x32_bf16(pf[mi], vh[nd][ks2], acc_o[mi][nd], 0, 0, 0);
          acc_o[mi][nd] = __builtin_amdgcn_mfma_f32_16x16x32_bf16(pf[mi], vl2[nd][ks2], acc_o[mi][nd], 0, 0, 0);
        }
    }
    __builtin_amdgcn_s_setprio(0);
  }
#pragma unroll
  for (int mi = 0; mi < 2; ++mi)
#pragma unroll
    for (int nd = 0; nd < 4; ++nd)
#pragma unroll
      for (int r = 0; r < 4; ++r) {
        const int row = q0 + mi * 16 + rg * 4 + r;
        const int d = h * 64 + nd * 16 + cl;
        Op[((size_t)b * SEQ + row) * HDIM + d] = acc_o[mi][nd][r];
      }
  if (sr == 0) {
#pragma unroll
    for (int mi = 0; mi < 2; ++mi)
#pragma unroll
      for (int r = 0; r < 4; ++r) {
        const int row = q0 + mi * 16 + rg * 4 + r;
        mlp[(size_t)(b * NHEAD + h) * SEQ + row] = make_float2(m_run[mi][r], l_run[mi][r]);
      }
  }
}

// ============ combine two KV-half partials -> split-bf16 ctx (fused) ============
__global__ __launch_bounds__(256) void combine_split(
    const float* __restrict__ O0, const float* __restrict__ O1,
    const float2* __restrict__ ml0, const float2* __restrict__ ml1,
    short* __restrict__ Ch, short* __restrict__ Cl)
{
  const int t = blockIdx.x;
  const int b = t >> 10, s = t & 1023;
  const int tid = threadIdx.x;
#pragma unroll
  for (int i = 0; i < 3; ++i) {
    const int idx = tid + i * 256;
    const int h = idx >> 6;
    const float2 a0 = ml0[(size_t)(b * NHEAD + h) * SEQ + s];
    const float2 a1 = ml1[(size_t)(b * NHEAD + h) * SEQ + s];
    const float mm = fmaxf(a0.x, a1.x);
    const float w0 = __expf(a0.x - mm), w1 = __expf(a1.x - mm);
    const float denom = a0.y * w0 + a1.y * w1;
    const size_t o = (size_t)t * HDIM + idx;
    const float v = (O0[o] * w0 + O1[o] * w1) / denom;
    const short hh = f2bf(v);
    Ch[o] = hh;
    Cl[o] = f2bf(v - bf2f(hh));
  }
}

// ============ transpose + f32->bf16 (expert weights) ============
__global__ __launch_bounds__(256) void transpose_to_bf16(
    const float* __restrict__ W, short* __restrict__ WT, int K, int N)
{
  const size_t off = (size_t)blockIdx.z * (size_t)K * N;
  const float* Wp = W + off;
  short* WTp = WT + off;
  __shared__ float t[32][33];
  const int tid = threadIdx.x;
  const int tx = tid & 31, ty = tid >> 5;
  const int n0 = blockIdx.x * 32, k0 = blockIdx.y * 32;
#pragma unroll
  for (int r = 0; r < 4; ++r)
    t[ty + r * 8][tx] = Wp[(size_t)(k0 + ty + r * 8) * N + n0 + tx];
  __syncthreads();
#pragma unroll
  for (int r = 0; r < 4; ++r)
    WTp[(size_t)(n0 + ty + r * 8) * K + k0 + tx] = f2bf(t[tx][ty + r * 8]);
}

// ============ expert up-proj: single-buffer (16 KB LDS), compact padded grid
// (REVERTED to R23: depth-2 cut occupancy 9->4 blocks/CU, MfmaUtil 9.9%) ============
__global__ __launch_bounds__(256) void expert_up_mfma(
    const short* __restrict__ Abf, const short* __restrict__ WiT,
    const float* __restrict__ bi, const int* __restrict__ perm,
    const int* __restrict__ offs, short* __restrict__ interb)
{
  const int row0 = blockIdx.x * 128;
  if (row0 >= offs[NEXP]) return;
  int e = 0;
  while (offs[e + 1] <= row0) ++e;
  __shared__ __align__(16) short lA[4096];
  __shared__ __align__(16) short lB[4096];
  __shared__ int toks[128];
  const int tid = threadIdx.x;
  const int w = tid >> 6, lane = tid & 63;
  const int wr = w >> 1, wc = w & 1;
  const int col0 = blockIdx.y * 128;
  if (tid < 128) toks[tid] = perm[row0 + tid];   // pads already -1
  __syncthreads();
  const int sr = lane & 15, kg = lane >> 4;
  int t0 = toks[2 * w * 16 + sr];        if (t0 < 0) t0 = toks[0];
  int t1 = toks[(2 * w + 1) * 16 + sr];  if (t1 < 0) t1 = toks[0];
  const size_t a0 = (size_t)t0 * HDIM + kg * 8;
  const size_t a1 = (size_t)t1 * HDIM + kg * 8;
  const short* Bt = WiT + (size_t)e * FDIM * HDIM;
  const size_t b0 = (size_t)(col0 + 2 * w * 16 + sr) * HDIM + kg * 8;
  const size_t b1 = b0 + (size_t)16 * HDIM;
  const int d0 = (2 * w) * 512, d1 = (2 * w + 1) * 512;
#define STAGE_E(k0) do { \
    gload16(Abf + a0 + (k0), &lA[d0]); \
    gload16(Abf + a1 + (k0), &lA[d1]); \
    gload16(Bt + b0 + (k0), &lB[d0]); \
    gload16(Bt + b1 + (k0), &lB[d1]); \
  } while (0)
  f32x4 acc[4][4] = {};
  STAGE_E(0);
  pipe_wait_barrier();
  for (int t = 0; t < 24; ++t) {
    s16x8 af[4], bg[4];
#pragma unroll
    for (int i = 0; i < 4; ++i) {
      af[i] = *(const s16x8*)&lA[(wr * 4 + i) * 512 + lane * 8];
      bg[i] = *(const s16x8*)&lB[(wc * 4 + i) * 512 + lane * 8];
    }
    __syncthreads();
    if (t < 23) STAGE_E((t + 1) * 32);
#pragma unroll
    for (int mi = 0; mi < 4; ++mi)
#pragma unroll
      for (int ni = 0; ni < 4; ++ni)
        acc[mi][ni] = __builtin_amdgcn_mfma_f32_16x16x32_bf16(af[mi], bg[ni], acc[mi][ni], 0, 0, 0);
    pipe_wait_barrier();
  }
#undef STAGE_E
  const int cl = lane & 15, rg = lane >> 4;
#pragma unroll
  for (int mi = 0; mi < 4; ++mi) {
#pragma unroll
    for (int r = 0; r < 4; ++r) {
      const int rl = wr * 64 + mi * 16 + rg * 4 + r;
      const int tok = toks[rl];
      if (tok < 0) continue;
#pragma unroll
      for (int ni = 0; ni < 4; ++ni) {
        const int c = col0 + wc * 64 + ni * 16 + cl;
        float v = acc[mi][ni][r] + bi[(size_t)e * FDIM + c];
        v = 0.5f * v * (1.0f + erff(v * 0.70710678118654752f));
        interb[(size_t)tok * FDIM + c] = f2bf(v);
      }
    }
  }
}

// ============ down-proj: single-buffer (16 KB LDS), SPLIT-K x2
// (REVERTED to R23: 8 blocks/CU beat the depth-2 pipeline here) ============
__global__ __launch_bounds__(256) void wo_mfma(
    const short* __restrict__ Ab, const short* __restrict__ BT,
    const float* __restrict__ bias, float* __restrict__ C0, float* __restrict__ C1)
{
  __shared__ __align__(16) short lA[4096];
  __shared__ __align__(16) short lB[4096];
  const int tid = threadIdx.x;
  const int w = tid >> 6, lane = tid & 63;
  const int wr = w >> 1, wc = w & 1;
  const int row0 = blockIdx.y * 128, col0 = blockIdx.x * 128;
  const int z = blockIdx.z;
  const int kbase = z * 1536;
  const int sr = lane & 15, kg = lane >> 4;
  const size_t a0 = (size_t)(row0 + 2 * w * 16 + sr) * FDIM + kbase + kg * 8;
  const size_t a1 = a0 + (size_t)16 * FDIM;
  const size_t b0 = (size_t)(col0 + 2 * w * 16 + sr) * FDIM + kbase + kg * 8;
  const size_t b1 = b0 + (size_t)16 * FDIM;
  const int d0 = (2 * w) * 512, d1 = (2 * w + 1) * 512;
#define STAGE_W(k0) do { \
    gload16(Ab + a0 + (k0), &lA[d0]); \
    gload16(Ab + a1 + (k0), &lA[d1]); \
    gload16(BT + b0 + (k0), &lB[d0]); \
    gload16(BT + b1 + (k0), &lB[d1]); \
  } while (0)
  f32x4 acc[4][4] = {};
  STAGE_W(0);
  pipe_wait_barrier();
  for (int t = 0; t < 48; ++t) {
    s16x8 af[4], bg[4];
#pragma unroll
    for (int i = 0; i < 4; ++i) {
      af[i] = *(const s16x8*)&lA[(wr * 4 + i) * 512 + lane * 8];
      bg[i] = *(const s16x8*)&lB[(wc * 4 + i) * 512 + lane * 8];
    }
    __syncthreads();
    if (t < 47) STAGE_W((t + 1) * 32);
#pragma unroll
    for (int mi = 0; mi < 4; ++mi)
#pragma unroll
      for (int ni = 0; ni < 4; ++ni)
        acc[mi][ni] = __builtin_amdgcn_mfma_f32_16x16x32_bf16(af[mi], bg[ni], acc[mi][ni], 0, 0, 0);
    pipe_wait_barrier();
  }
#undef STAGE_W
  float* C = z ? C1 : C0;
  const int cl = lane & 15, rg = lane >> 4;
#pragma unroll
  for (int mi = 0; mi < 4; ++mi) {
#pragma unroll
    for (int r = 0; r < 4; ++r) {
      const int row = row0 + wr * 64 + mi * 16 + rg * 4 + r;
#pragma unroll
      for (int ni = 0; ni < 4; ++ni) {
        const int c = col0 + wc * 64 + ni * 16 + cl;
        C[(size_t)row * HDIM + c] = acc[mi][ni][r] + (z ? 0.f : bias[c]);
      }
    }
  }
}

// ============ two-partial add + residual + LayerNorm ============
__global__ __launch_bounds__(256) void add2_ln_kernel(
    const float* __restrict__ X1, const float* __restrict__ X2,
    const float* __restrict__ R, const float* __restrict__ g,
    const float* __restrict__ bb, float* __restrict__ out)
{
  const int t = blockIdx.x;
  const int tid = threadIdx.x;
  const float* x1 = X1 + (size_t)t * HDIM;
  const float* x2 = X2 + (size_t)t * HDIM;
  const float* r = R + (size_t)t * HDIM;
  float v[3];
  float sum = 0.f, ssq = 0.f;
#pragma unroll
  for (int i = 0; i < 3; ++i) {
    const float val = x1[tid + i * 256] + x2[tid + i * 256] + r[tid + i * 256];
    v[i] = val;
    sum += val;
    ssq += val * val;
  }
#pragma unroll
  for (int o = 32; o > 0; o >>= 1) {
    sum += __shfl_down(sum, o);
    ssq += __shfl_down(ssq, o);
  }
  __shared__ float red[10];
  const int wid = tid >> 6, lane = tid & 63;
  if (lane == 0) { red[wid] = sum; red[4 + wid] = ssq; }
  __syncthreads();
  if (tid == 0) {
    const float s = red[0] + red[1] + red[2] + red[3];
    const float q = red[4] + red[5] + red[6] + red[7];
    const float mean = s * (1.f / HDIM);
    const float var = q * (1.f / HDIM) - mean * mean;
    red[8] = mean;
    red[9] = rsqrtf(fmaxf(var, 0.f) + 1e-12f);
  }
  __syncthreads();
  const float mean = red[8], rstd = red[9];
#pragma unroll
  for (int i = 0; i < 3; ++i) {
    const int idx = tid + i * 256;
    out[(size_t)t * HDIM + idx] = g[idx] * (v[i] - mean) * rstd + bb[idx];
  }
}

// ============ LN1 variant: also emits bf16 copy (fuses convert_bf16) ============
__global__ __launch_bounds__(256) void add2_ln_bf16_kernel(
    const float* __restrict__ X1, const float* __restrict__ X2,
    const float* __restrict__ R, const float* __restrict__ g,
    const float* __restrict__ bb, float* __restrict__ out, short* __restrict__ outb)
{
  const int t = blockIdx.x;
  const int tid = threadIdx.x;
  const float* x1 = X1 + (size_t)t * HDIM;
  const float* x2 = X2 + (size_t)t * HDIM;
  const float* r = R + (size_t)t * HDIM;
  float v[3];
  float sum = 0.f, ssq = 0.f;
#pragma unroll
  for (int i = 0; i < 3; ++i) {
    const float val = x1[tid + i * 256] + x2[tid + i * 256] + r[tid + i * 256];
    v[i] = val;
    sum += val;
    ssq += val * val;
  }
#pragma unroll
  for (int o = 32; o > 0; o >>= 1) {
    sum += __shfl_down(sum, o);
    ssq += __shfl_down(ssq, o);
  }
  __shared__ float red[10];
  const int wid = tid >> 6, lane = tid & 63;
  if (lane == 0) { red[wid] = sum; red[4 + wid] = ssq; }
  __syncthreads();
  if (tid == 0) {
    const float s = red[0] + red[1] + red[2] + red[3];
    const float q = red[4] + red[5] + red[6] + red[7];
    const float mean = s * (1.f / HDIM);
    const float var = q * (1.f / HDIM) - mean * mean;
    red[8] = mean;
    red[9] = rsqrtf(fmaxf(var, 0.f) + 1e-12f);
  }
  __syncthreads();
  const float mean = red[8], rstd = red[9];
#pragma unroll
  for (int i = 0; i < 3; ++i) {
    const int idx = tid + i * 256;
    const float o = g[idx] * (v[i] - mean) * rstd + bb[idx];
    out[(size_t)t * HDIM + idx] = o;
    outb[(size_t)t * HDIM + idx] = f2bf(o);
  }
}

// ============ router (f32 — keeps argmax path bit-identical) ============
__global__ __launch_bounds__(256) void router_kernel(
    const float* __restrict__ X, const float* __restrict__ Wr,
    const float* __restrict__ br, float* __restrict__ scores_out,
    int* __restrict__ expert, int* __restrict__ counts)
{
  const int wid = threadIdx.x >> 6, lane = threadIdx.x & 63;
  const int tok = blockIdx.x * 4 + wid;
  const float* x = X + (size_t)tok * HDIM;
  float acc[8] = {};
  for (int k0 = 0; k0 < HDIM; k0 += 64) {
    const float xv = x[k0 + lane];
    const float* wrow = Wr + (size_t)(k0 + lane) * NEXP;
    const float4 w0 = *reinterpret_cast<const float4*>(wrow);
    const float4 w1 = *reinterpret_cast<const float4*>(wrow + 4);
    acc[0] = fmaf(xv, w0.x, acc[0]);
    acc[1] = fmaf(xv, w0.y, acc[1]);
    acc[2] = fmaf(xv, w0.z, acc[2]);
    acc[3] = fmaf(xv, w0.w, acc[3]);
    acc[4] = fmaf(xv, w1.x, acc[4]);
    acc[5] = fmaf(xv, w1.y, acc[5]);
    acc[6] = fmaf(xv, w1.z, acc[6]);
    acc[7] = fmaf(xv, w1.w, acc[7]);
  }
#pragma unroll
  for (int e = 0; e < 8; ++e)
#pragma unroll
    for (int o = 32; o > 0; o >>= 1) acc[e] += __shfl_down(acc[e], o);
  if (lane == 0) {
    float mx = -3.0e38f;
#pragma unroll
    for (int e = 0; e < 8; ++e) { acc[e] += br[e]; mx = fmaxf(mx, acc[e]); }
    float sum = 0.f;
#pragma unroll
    for (int e = 0; e < 8; ++e) { acc[e] = expf(acc[e] - mx); sum += acc[e]; }
    const float inv = 1.f / sum;
    int best = 0;
    float bv = acc[0];
#pragma unroll
    for (int e = 0; e < 8; ++e) {
      const float p = acc[e] * inv;
      scores_out[(size_t)tok * NEXP + e] = p;
      if (acc[e] > bv) { bv = acc[e]; best = e; }
    }
    expert[tok] = best;
    atomicAdd(&counts[best], 1);
  }
}

// padded prefix: each expert segment rounded up to a multiple of 128
__global__ void offsets_kernel(const int* __restrict__ counts, int* __restrict__ offs)
{
  if (threadIdx.x == 0 && blockIdx.x == 0) {
    int a = 0;
    for (int e = 0; e < NEXP; ++e) {
      offs[e] = a;
      a += ((counts[e] + 127) >> 7) << 7;
    }
    offs[NEXP] = a;
  }
}

__global__ __launch_bounds__(256) void scatter_kernel(
    const int* __restrict__ expert, const int* __restrict__ offs,
    int* __restrict__ cursor, int* __restrict__ perm)
{
  const int t = blockIdx.x * 256 + threadIdx.x;
  if (t >= TOKS) return;
  const int e = expert[t];
  const int pos = atomicAdd(&cursor[e], 1);
  perm[offs[e] + pos] = t;
}

extern "C" void kernel_launch(void* const* d_in, const int* in_sizes, int n_in,
                              void* d_out, int out_size, void* d_ws, size_t ws_size,
                              hipStream_t stream) {
  const float* hidden = (const float*)d_in[0];
  const float* Wq  = (const float*)d_in[1];
  const float* bq  = (const float*)d_in[2];
  const float* Wk  = (const float*)d_in[3];
  const float* bk  = (const float*)d_in[4];
  const float* Wv  = (const float*)d_in[5];
  const float* bv  = (const float*)d_in[6];
  const float* Wao = (const float*)d_in[7];
  const float* bao = (const float*)d_in[8];
  const float* ln1g = (const float*)d_in[9];
  const float* ln1b = (const float*)d_in[10];
  const float* Wr  = (const float*)d_in[11];
  const float* br  = (const float*)d_in[12];
  const float* Wi  = (const float*)d_in[13];
  const float* bi  = (const float*)d_in[14];
  const float* Wo  = (const float*)d_in[15];
  const float* bo  = (const float*)d_in[16];
  const float* ln2g = (const float*)d_in[17];
  const float* ln2b = (const float*)d_in[18];

  float* out = (float*)d_out;
  float* scores_out = out + (size_t)TOKS * HDIM;

  const size_t M1 = (size_t)TOKS * HDIM;     // 6.29M floats
  const size_t HW = (size_t)HDIM * HDIM;
  float* ws = (float*)d_ws;
  // ---- arena (float offsets, by liveness) ----
  short* QKhb = (short*)ws;
  short* QKlb = (short*)(ws + M1);
  short* VThb = (short*)(ws + 2 * M1);
  short* VTlb = VThb + (size_t)BATCH * NHEAD * 64 * 1024;
  float* O0b  = ws + 3 * M1;
  float* O1b  = ws + 4 * M1;
  float* bqkv = ws + 3 * M1;                 // dead before attention writes O0
  short* Hh = (short*)(ws + 4 * M1);
  short* Hl = Hh + M1;
  short* Ch = (short*)(ws + 2 * M1);         // ctx split (VT region, dead after attention)
  short* Cl = Ch + M1;
  short* wt = (short*)(ws + 5 * M1);
  short* WqkvhT = wt;
  short* WqkvlT = wt + 3 * HW;
  short* WaohT  = wt + 6 * HW;
  short* WaolT  = wt + 7 * HW;
  float2* ml0 = (float2*)(ws + 5 * M1 + 4 * HW);
  float2* ml1 = ml0 + (size_t)BATCH * NHEAD * SEQ;
  float* aoproj0  = ws;                      // QKhb region (dead after attention)
  float* aoproj1  = ws + 3 * M1;             // O0 region (dead after combine)
  float* attn_out = ws + M1;                 // QKlb region
  float* tmp2a    = ws;
  float* tmp2b    = ws + 3 * M1;
  short* Abf    = (short*)(ws + 2 * M1);     // expert phase (Ch/Cl dead after AO)
  short* WiT    = Abf + M1;
  short* WoT    = WiT + (size_t)NEXP * FDIM * HDIM;
  short* interb = WoT + (size_t)HDIM * FDIM;
  int* ints   = (int*)(interb + (size_t)TOKS * FDIM);
  int* perm   = ints;                        // PERMSZ (padded)
  int* expert = ints + PERMSZ;
  int* counts = expert + TOKS;
  int* offs   = counts + NEXP;               // NEXP+1 padded prefix
  int* cursor = offs + NEXP + 1;

  hipMemsetAsync(counts, 0, (NEXP + NEXP + 1 + NEXP) * sizeof(int), stream);
  hipMemsetAsync(perm, 0xFF, PERMSZ * sizeof(int), stream);   // pads = -1
  hipMemcpyAsync(bqkv,        bq, HDIM * sizeof(float), hipMemcpyDeviceToDevice, stream);
  hipMemcpyAsync(bqkv + 768,  bk, HDIM * sizeof(float), hipMemcpyDeviceToDevice, stream);
  hipMemcpyAsync(bqkv + 1536, bv, HDIM * sizeof(float), hipMemcpyDeviceToDevice, stream);

  const dim3 blk(256);
  // --- split prep ---
  convert_split<<<dim3(TOKS * HDIM / 4 / 256), blk, 0, stream>>>(hidden, Hh, Hl, TOKS * HDIM / 4);
  transpose_split<<<dim3(24, 24), blk, 0, stream>>>(Wq,  WqkvhT,          WqkvlT,          HDIM, HDIM);
  transpose_split<<<dim3(24, 24), blk, 0, stream>>>(Wk,  WqkvhT + HW,     WqkvlT + HW,     HDIM, HDIM);
  transpose_split<<<dim3(24, 24), blk, 0, stream>>>(Wv,  WqkvhT + 2 * HW, WqkvlT + 2 * HW, HDIM, HDIM);
  transpose_split<<<dim3(24, 24), blk, 0, stream>>>(Wao, WaohT,           WaolT,           HDIM, HDIM);

  // --- fused QKV projection (depth-2 counted-vmcnt pipeline + XCD swizzle) ---
  qkv_split_mfma<<<dim3(2304 / 128, TOKS / 128), blk, 0, stream>>>(
      Hh, Hl, WqkvhT, WqkvlT, bqkv, QKhb, QKlb, VThb, VTlb);

  // --- MFMA flash attention (bf16 P, Kh-only QK), KV-split x2, 2-wave blocks ---
  attention_part<<<dim3((SEQ / 64) * 2, NHEAD, BATCH), dim3(128), 0, stream>>>(
      QKhb, QKlb, VThb, VTlb, O0b, O1b, ml0, ml1);
  combine_split<<<dim3(TOKS), blk, 0, stream>>>(O0b, O1b, ml0, ml1, Ch, Cl);

  // --- AO projection (single-buf 32KB, split-K x2) + LN1 (fused bf16 emit -> Abf) ---
  gemm_splitk_staged<<<dim3(HDIM / 128, TOKS / 128, 2), blk, 0, stream>>>(
      Ch, Cl, WaohT, WaolT, bao, aoproj0, aoproj1, HDIM, HDIM);
  add2_ln_bf16_kernel<<<dim3(TOKS), blk, 0, stream>>>(
      aoproj0, aoproj1, hidden, ln1g, ln1b, attn_out, Abf);

  // --- router + dispatch (padded permutation) ---
  router_kernel<<<dim3(TOKS / 4), blk, 0, stream>>>(attn_out, Wr, br, scores_out, expert, counts);
  offsets_kernel<<<dim3(1), dim3(64), 0, stream>>>(counts, offs);
  scatter_kernel<<<dim3(TOKS / 256), blk, 0, stream>>>(expert, offs, cursor, perm);

  // --- expert FFN (single-buf 16KB kernels; split-K down-proj) ---
  transpose_to_bf16<<<dim3(FDIM / 32, HDIM / 32, NEXP), blk, 0, stream>>>(Wi, WiT, HDIM, FDIM);
  transpose_to_bf16<<<dim3(HDIM / 32, FDIM / 32, 1), blk, 0, stream>>>(Wo, WoT, FDIM, HDIM);

  expert_up_mfma<<<dim3(PERMSZ / 128, FDIM / 128), blk, 0, stream>>>(
      Abf, WiT, bi, perm, offs, interb);
  wo_mfma<<<dim3(HDIM / 128, TOKS / 128, 2), blk, 0, stream>>>(interb, WoT, bo, tmp2a, tmp2b);
  add2_ln_kernel<<<dim3(TOKS), blk, 0, stream>>>(tmp2a, tmp2b, attn_out, ln2g, ln2b, out);
}

// Round 26
// 773.894 us; speedup vs baseline: 1.0753x; 1.0393x over previous
//
#include <hip/hip_runtime.h>
#include <math.h>
#include <stdint.h>

#define TOKS 8192
#define HDIM 768
#define FDIM 3072
#define NEXP 8
#define NHEAD 12
#define SEQ 1024
#define BATCH 8
#define PERMSZ 9216   // 8192 + 8*128 worst-case padding

typedef __attribute__((ext_vector_type(8))) short s16x8;   // 8 bf16 = 4 VGPR
typedef __attribute__((ext_vector_type(4))) short s16x4;
typedef __attribute__((ext_vector_type(4))) float f32x4;

__device__ __forceinline__ short f2bf(float f) {
  uint32_t u = __float_as_uint(f);
  uint32_t r = (u + 0x7fffu + ((u >> 16) & 1u)) >> 16;   // RTN-even
  return (short)(r & 0xffffu);
}
__device__ __forceinline__ float bf2f(short h) {
  return __uint_as_float(((uint32_t)(uint16_t)h) << 16);
}
__device__ __forceinline__ void gload16(const void* g, void* l) {
  __builtin_amdgcn_global_load_lds(
      (const __attribute__((address_space(1))) uint32_t*)g,
      (__attribute__((address_space(3))) uint32_t*)l, 16, 0, 0);
}
// drain outstanding global->LDS DMA, then workgroup barrier.
__device__ __forceinline__ void pipe_wait_barrier() {
  asm volatile("s_waitcnt vmcnt(0)" ::: "memory");
  __builtin_amdgcn_s_barrier();
}
// LDS-reads-retired fence + raw barrier (no vmcnt drain — keeps DMA in flight).
__device__ __forceinline__ void lds_read_barrier() {
  asm volatile("s_waitcnt lgkmcnt(0)" ::: "memory");
  __builtin_amdgcn_s_barrier();
}

// ============ f32 -> (hi,lo) bf16 split, 4 elems/thread ============
__global__ __launch_bounds__(256) void convert_split(
    const float* __restrict__ X, short* __restrict__ Xh, short* __restrict__ Xl, int n4)
{
  const int i = blockIdx.x * 256 + threadIdx.x;
  if (i >= n4) return;
  const float4 v = ((const float4*)X)[i];
  const float a[4] = {v.x, v.y, v.z, v.w};
  s16x4 h, l;
#pragma unroll
  for (int j = 0; j < 4; ++j) {
    h[j] = f2bf(a[j]);
    l[j] = f2bf(a[j] - bf2f(h[j]));
  }
  ((s16x4*)Xh)[i] = h;
  ((s16x4*)Xl)[i] = l;
}

// ============ transpose + split: WT{h,l}[n][k] = split(W[k][n]) ============
__global__ __launch_bounds__(256) void transpose_split(
    const float* __restrict__ W, short* __restrict__ WTh, short* __restrict__ WTl,
    int K, int N)
{
  __shared__ float t[32][33];
  const int tid = threadIdx.x;
  const int tx = tid & 31, ty = tid >> 5;
  const int n0 = blockIdx.x * 32, k0 = blockIdx.y * 32;
#pragma unroll
  for (int r = 0; r < 4; ++r)
    t[ty + r * 8][tx] = W[(size_t)(k0 + ty + r * 8) * N + n0 + tx];
  __syncthreads();
#pragma unroll
  for (int r = 0; r < 4; ++r) {
    const float v = t[tx][ty + r * 8];
    const short h = f2bf(v);
    WTh[(size_t)(n0 + ty + r * 8) * K + k0 + tx] = h;
    WTl[(size_t)(n0 + ty + r * 8) * K + k0 + tx] = f2bf(v - bf2f(h));
  }
}

// ============ QKV split-GEMM: depth-2 counted-vmcnt pipeline (64 KB LDS),
// raw barriers (no vmcnt drain mid-loop); XCD-swizzled grid; Q pre-scaled 1/8.
// (KEPT from R24: 182->162 us. Long 24-step loop + residency-insensitive.) ====
__global__ __launch_bounds__(256) void qkv_split_mfma(
    const short* __restrict__ Ah, const short* __restrict__ Al,
    const short* __restrict__ BhT, const short* __restrict__ BlT,
    const float* __restrict__ bias,
    short* __restrict__ QKh, short* __restrict__ QKl,
    short* __restrict__ VTh, short* __restrict__ VTl)
{
  const int K = 768;
  __shared__ __align__(16) short lAh[2][4096];
  __shared__ __align__(16) short lAl[2][4096];
  __shared__ __align__(16) short lBh[2][4096];
  __shared__ __align__(16) short lBl[2][4096];
  // XCD swizzle: nwg = 18*64 = 1152, chunk = 144 per XCD (bijective)
  const int dsp = blockIdx.x + 18 * blockIdx.y;
  const int orig = (dsp & 7) * 144 + (dsp >> 3);
  const int bx = orig % 18, by = orig / 18;
  const int tid = threadIdx.x;
  const int w = tid >> 6, lane = tid & 63;
  const int wr = w >> 1, wc = w & 1;
  const int row0 = by * 128, col0 = bx * 128;
  const int sr = lane & 15, kg = lane >> 4;
  const size_t a0 = (size_t)(row0 + 2 * w * 16 + sr) * K + kg * 8;
  const size_t a1 = a0 + (size_t)16 * K;
  const size_t b0 = (size_t)(col0 + 2 * w * 16 + sr) * K + kg * 8;
  const size_t b1 = b0 + (size_t)16 * K;
  const int d0 = (2 * w) * 512, d1 = (2 * w + 1) * 512;
#define STAGE_Q(bu, k0) do { \
    gload16(Ah + a0 + (k0), &lAh[bu][d0]); \
    gload16(Ah + a1 + (k0), &lAh[bu][d1]); \
    gload16(Al + a0 + (k0), &lAl[bu][d0]); \
    gload16(Al + a1 + (k0), &lAl[bu][d1]); \
    gload16(BhT + b0 + (k0), &lBh[bu][d0]); \
    gload16(BhT + b1 + (k0), &lBh[bu][d1]); \
    gload16(BlT + b0 + (k0), &lBl[bu][d0]); \
    gload16(BlT + b1 + (k0), &lBl[bu][d1]); \
  } while (0)
  f32x4 acc[4][4] = {};
  STAGE_Q(0, 0);
  STAGE_Q(1, 32);
  asm volatile("s_waitcnt vmcnt(8)" ::: "memory");   // stage(0) landed; stage(1) in flight
  __builtin_amdgcn_s_barrier();
  for (int t = 0; t < 24; ++t) {
    const int cur = t & 1;
    s16x8 ah[4], al[4], bh[4], bl[4];
#pragma unroll
    for (int i = 0; i < 4; ++i) {
      ah[i] = *(const s16x8*)&lAh[cur][(wr * 4 + i) * 512 + lane * 8];
      al[i] = *(const s16x8*)&lAl[cur][(wr * 4 + i) * 512 + lane * 8];
      bh[i] = *(const s16x8*)&lBh[cur][(wc * 4 + i) * 512 + lane * 8];
      bl[i] = *(const s16x8*)&lBl[cur][(wc * 4 + i) * 512 + lane * 8];
    }
    lds_read_barrier();   // reads retired; buf[cur] free (DMA stays in flight!)
    if (t + 2 < 24) STAGE_Q(cur, (t + 2) * 32);   // depth-2 prefetch into freed buffer
#pragma unroll
    for (int mi = 0; mi < 4; ++mi)
#pragma unroll
      for (int ni = 0; ni < 4; ++ni) {
        acc[mi][ni] = __builtin_amdgcn_mfma_f32_16x16x32_bf16(ah[mi], bh[ni], acc[mi][ni], 0, 0, 0);
        acc[mi][ni] = __builtin_amdgcn_mfma_f32_16x16x32_bf16(ah[mi], bl[ni], acc[mi][ni], 0, 0, 0);
        acc[mi][ni] = __builtin_amdgcn_mfma_f32_16x16x32_bf16(al[mi], bh[ni], acc[mi][ni], 0, 0, 0);
      }
    // counted wait: stage(t+1) done, stage(t+2)'s 8 loads remain outstanding
    if (t + 2 < 24) asm volatile("s_waitcnt vmcnt(8)" ::: "memory");
    else            asm volatile("s_waitcnt vmcnt(0)" ::: "memory");
    __builtin_amdgcn_s_barrier();
  }
#undef STAGE_Q
  const int cl = lane & 15, rg = lane >> 4;
#pragma unroll
  for (int mi = 0; mi < 4; ++mi)
#pragma unroll
    for (int ni = 0; ni < 4; ++ni) {
      const int c = col0 + wc * 64 + ni * 16 + cl;
      const int rowb = row0 + wr * 64 + mi * 16 + rg * 4;
      // Q columns (c<768) pre-scaled by 1/8: exact power-of-2, commutes through
      // the bf16 split and the QK^T MFMA bit-exactly.
      const float qscale = (c < 768) ? 0.125f : 1.0f;
      s16x4 hv, lv;
#pragma unroll
      for (int r = 0; r < 4; ++r) {
        const float v = (acc[mi][ni][r] + bias[c]) * qscale;
        const short hh = f2bf(v);
        hv[r] = hh;
        lv[r] = f2bf(v - bf2f(hh));
      }
      if (c < 1536) {
#pragma unroll
        for (int r = 0; r < 4; ++r) {
          QKh[(size_t)(rowb + r) * 1536 + c] = hv[r];
          QKl[(size_t)(rowb + r) * 1536 + c] = lv[r];
        }
      } else {          // V column: transposed store VT[b][h][d][s]
        const int dall = c - 1536;
        const size_t vi = (((size_t)((rowb >> 10) * NHEAD + (dall >> 6))) * 64 + (dall & 63)) * 1024
                          + (rowb & 1023);
        *(s16x4*)(VTh + vi) = hv;
        *(s16x4*)(VTl + vi) = lv;
      }
    }
}

// ============ AO GEMM: single-buffer split-bf16 (32 KB LDS), SPLIT-K x2 ============
__global__ __launch_bounds__(256) void gemm_splitk_staged(
    const short* __restrict__ Ah, const short* __restrict__ Al,
    const short* __restrict__ BhT, const short* __restrict__ BlT,
    const float* __restrict__ bias, float* __restrict__ C0, float* __restrict__ C1,
    int N, int K)
{
  __shared__ __align__(16) short lAh[4096];
  __shared__ __align__(16) short lAl[4096];
  __shared__ __align__(16) short lBh[4096];
  __shared__ __align__(16) short lBl[4096];
  const int tid = threadIdx.x;
  const int w = tid >> 6, lane = tid & 63;
  const int wr = w >> 1, wc = w & 1;
  const int row0 = blockIdx.y * 128, col0 = blockIdx.x * 128;
  const int z = blockIdx.z;
  const int Khalf = K >> 1, koff = z * Khalf;
  const int sr = lane & 15, kg = lane >> 4;
  const size_t a0 = (size_t)(row0 + 2 * w * 16 + sr) * K + koff + kg * 8;
  const size_t a1 = a0 + (size_t)16 * K;
  const size_t b0 = (size_t)(col0 + 2 * w * 16 + sr) * K + koff + kg * 8;
  const size_t b1 = b0 + (size_t)16 * K;
  const int d0 = (2 * w) * 512, d1 = (2 * w + 1) * 512;
#define STAGE_K4(k0) do { \
    gload16(Ah + a0 + (k0), &lAh[d0]); \
    gload16(Ah + a1 + (k0), &lAh[d1]); \
    gload16(Al + a0 + (k0), &lAl[d0]); \
    gload16(Al + a1 + (k0), &lAl[d1]); \
    gload16(BhT + b0 + (k0), &lBh[d0]); \
    gload16(BhT + b1 + (k0), &lBh[d1]); \
    gload16(BlT + b0 + (k0), &lBl[d0]); \
    gload16(BlT + b1 + (k0), &lBl[d1]); \
  } while (0)
  f32x4 acc[4][4] = {};
  const int NT = Khalf >> 5;
  STAGE_K4(0);
  pipe_wait_barrier();
  for (int t = 0; t < NT; ++t) {
    s16x8 ah[4], al[4], bh[4], bl[4];
#pragma unroll
    for (int i = 0; i < 4; ++i) {
      ah[i] = *(const s16x8*)&lAh[(wr * 4 + i) * 512 + lane * 8];
      al[i] = *(const s16x8*)&lAl[(wr * 4 + i) * 512 + lane * 8];
      bh[i] = *(const s16x8*)&lBh[(wc * 4 + i) * 512 + lane * 8];
      bl[i] = *(const s16x8*)&lBl[(wc * 4 + i) * 512 + lane * 8];
    }
    __syncthreads();
    if (t + 1 < NT) STAGE_K4((t + 1) * 32);
#pragma unroll
    for (int mi = 0; mi < 4; ++mi)
#pragma unroll
      for (int ni = 0; ni < 4; ++ni) {
        acc[mi][ni] = __builtin_amdgcn_mfma_f32_16x16x32_bf16(ah[mi], bh[ni], acc[mi][ni], 0, 0, 0);
        acc[mi][ni] = __builtin_amdgcn_mfma_f32_16x16x32_bf16(ah[mi], bl[ni], acc[mi][ni], 0, 0, 0);
        acc[mi][ni] = __builtin_amdgcn_mfma_f32_16x16x32_bf16(al[mi], bh[ni], acc[mi][ni], 0, 0, 0);
      }
    pipe_wait_barrier();
  }
#undef STAGE_K4
  float* C = z ? C1 : C0;
  const int cl = lane & 15, rg = lane >> 4;
#pragma unroll
  for (int mi = 0; mi < 4; ++mi)
#pragma unroll
    for (int r = 0; r < 4; ++r) {
      const int row = row0 + wr * 64 + mi * 16 + rg * 4 + r;
#pragma unroll
      for (int ni = 0; ni < 4; ++ni) {
        const int c = col0 + wc * 64 + ni * 16 + cl;
        C[(size_t)row * N + c] = acc[mi][ni][r] + (z ? 0.f : bias[c]);
      }
    }
}

// ============ MFMA flash attention, KV-SPLIT x2 — TWO-WAVE blocks (10 KB LDS) ============
// P plain bf16; QK^T uses (Qh+Ql)*Kh only (Kl dropped: S err ~3e-3 abs, averaged to
// ~1e-4 in O by softmax over ~900 keys — router-safe class, same as bf16-P change).
__global__ __launch_bounds__(128, 2) void attention_part(
    const short* __restrict__ QKh, const short* __restrict__ QKl,
    const short* __restrict__ VTh, const short* __restrict__ VTl,
    float* __restrict__ O0, float* __restrict__ O1,
    float2* __restrict__ ml0, float2* __restrict__ ml1)
{
  __shared__ __align__(16) short lPh[2][2560];   // [wave][(mi*2+ks2)*640 + q*40 + koff]
  const int tid = threadIdx.x;
  const int w = tid >> 6, lane = tid & 63;
  // XCD swizzle: nwg = 32*12*8 = 3072, chunk = 384 (= one batch per XCD)
  const int dsp = blockIdx.x + 32 * (blockIdx.y + 12 * blockIdx.z);
  const int orig = (dsp & 7) * 384 + (dsp >> 3);
  const int wx = orig & 31;
  const int b = orig / 384, h = (orig >> 5) % 12;
  const int z = wx & 1;
  const int q0 = (wx >> 1) * 64 + w * 32;    // this wave's 32 q-rows
  const int kv0 = z * 512;
  const int sr = lane & 15, kg = lane >> 4;
  const int cl = sr, rg = kg;
  short* myPh = lPh[w];
  float* Op = z ? O1 : O0;
  float2* mlp = z ? ml1 : ml0;

  s16x8 qh[2][2], ql[2][2];
  {
    const size_t qbase = ((size_t)b * SEQ + q0 + sr) * 1536 + h * 64 + kg * 8;
#pragma unroll
    for (int mi = 0; mi < 2; ++mi)
#pragma unroll
      for (int ks = 0; ks < 2; ++ks) {
        const size_t o = qbase + (size_t)mi * (16 * 1536) + ks * 32;
        qh[mi][ks] = *(const s16x8*)(QKh + o);
        ql[mi][ks] = *(const s16x8*)(QKl + o);
      }
  }
  float m_run[2][4], l_run[2][4];
#pragma unroll
  for (int mi = 0; mi < 2; ++mi)
#pragma unroll
    for (int r = 0; r < 4; ++r) { m_run[mi][r] = -3.0e38f; l_run[mi][r] = 0.f; }
  f32x4 acc_o[2][4] = {};

  for (int kt = kv0; kt < kv0 + 512; kt += 64) {
    s16x8 kh[4][2];
    {
      const size_t kbase = ((size_t)b * SEQ + kt + sr) * 1536 + 768 + h * 64 + kg * 8;
#pragma unroll
      for (int ni = 0; ni < 4; ++ni)
#pragma unroll
        for (int ks = 0; ks < 2; ++ks) {
          const size_t o = kbase + (size_t)ni * (16 * 1536) + ks * 32;
          kh[ni][ks] = *(const s16x8*)(QKh + o);
        }
    }
    f32x4 accs[2][4] = {};
    __builtin_amdgcn_s_setprio(1);
#pragma unroll
    for (int ks = 0; ks < 2; ++ks)
#pragma unroll
      for (int ni = 0; ni < 4; ++ni)
#pragma unroll
        for (int mi = 0; mi < 2; ++mi) {
          accs[mi][ni] = __builtin_amdgcn_mfma_f32_16x16x32_bf16(qh[mi][ks], kh[ni][ks], accs[mi][ni], 0, 0, 0);
          accs[mi][ni] = __builtin_amdgcn_mfma_f32_16x16x32_bf16(ql[mi][ks], kh[ni][ks], accs[mi][ni], 0, 0, 0);
        }
    __builtin_amdgcn_s_setprio(0);
    s16x8 vh[4][2], vl2[4][2];
    {
      const size_t vbase = (((size_t)(b * NHEAD + h)) * 64 + sr) * 1024 + kt + kg * 8;
#pragma unroll
      for (int nd = 0; nd < 4; ++nd)
#pragma unroll
        for (int ks2 = 0; ks2 < 2; ++ks2) {
          const size_t o = vbase + (size_t)nd * (16 * 1024) + ks2 * 32;
          vh[nd][ks2] = *(const s16x8*)(VTh + o);
          vl2[nd][ks2] = *(const s16x8*)(VTl + o);
        }
    }
#pragma unroll
    for (int mi = 0; mi < 2; ++mi)
#pragma unroll
      for (int r = 0; r < 4; ++r) {
        float mx = fmaxf(fmaxf(accs[mi][0][r], accs[mi][1][r]),
                         fmaxf(accs[mi][2][r], accs[mi][3][r]));
        mx = fmaxf(mx, __shfl_xor(mx, 1));
        mx = fmaxf(mx, __shfl_xor(mx, 2));
        mx = fmaxf(mx, __shfl_xor(mx, 4));
        mx = fmaxf(mx, __shfl_xor(mx, 8));
        const float mn = fmaxf(m_run[mi][r], mx);
        const float c = __expf(m_run[mi][r] - mn);
        m_run[mi][r] = mn;
        l_run[mi][r] *= c;
#pragma unroll
        for (int nd = 0; nd < 4; ++nd) acc_o[mi][nd][r] *= c;
        float sum = 0.f;
#pragma unroll
        for (int ni = 0; ni < 4; ++ni) {
          const float p = __expf(accs[mi][ni][r] - mn);
          const short hh = f2bf(p);
          sum += bf2f(hh);   // consistent with PV numerator (rounded P)
          const int idx = (mi * 2 + (ni >> 1)) * 640 + (rg * 4 + r) * 40 + (ni & 1) * 16 + cl;
          myPh[idx] = hh;
        }
        sum += __shfl_xor(sum, 1);
        sum += __shfl_xor(sum, 2);
        sum += __shfl_xor(sum, 4);
        sum += __shfl_xor(sum, 8);
        l_run[mi][r] += sum;
      }
    __builtin_amdgcn_s_setprio(1);
#pragma unroll
    for (int ks2 = 0; ks2 < 2; ++ks2) {
      s16x8 pf[2];
#pragma unroll
      for (int mi = 0; mi < 2; ++mi) {
        const int ra = (mi * 2 + ks2) * 640 + sr * 40 + kg * 8;
        pf[mi] = *(const s16x8*)&myPh[ra];
      }
#pragma unroll
      for (int nd = 0; nd < 4; ++nd)
#pragma unroll
        for (int mi = 0; mi < 2; ++mi) {
          acc_o[mi][nd] = __builtin_amdgcn_mfma_f32_16x16x32_bf16(pf[mi], vh[nd][ks2], acc_o[mi][nd], 0, 0, 0);
          acc_o[mi][nd] = __builtin_amdgcn_mfma_f32_16x16x32_bf16(pf[mi], vl2[nd][ks2], acc_o[mi][nd], 0, 0, 0);
        }
    }
    __builtin_amdgcn_s_setprio(0);
  }
#pragma unroll
  for (int mi = 0; mi < 2; ++mi)
#pragma unroll
    for (int nd = 0; nd < 4; ++nd)
#pragma unroll
      for (int r = 0; r < 4; ++r) {
        const int row = q0 + mi * 16 + rg * 4 + r;
        const int d = h * 64 + nd * 16 + cl;
        Op[((size_t)b * SEQ + row) * HDIM + d] = acc_o[mi][nd][r];
      }
  if (sr == 0) {
#pragma unroll
    for (int mi = 0; mi < 2; ++mi)
#pragma unroll
      for (int r = 0; r < 4; ++r) {
        const int row = q0 + mi * 16 + rg * 4 + r;
        mlp[(size_t)(b * NHEAD + h) * SEQ + row] = make_float2(m_run[mi][r], l_run[mi][r]);
      }
  }
}

// ============ combine two KV-half partials -> split-bf16 ctx (fused) ============
__global__ __launch_bounds__(256) void combine_split(
    const float* __restrict__ O0, const float* __restrict__ O1,
    const float2* __restrict__ ml0, const float2* __restrict__ ml1,
    short* __restrict__ Ch, short* __restrict__ Cl)
{
  const int t = blockIdx.x;
  const int b = t >> 10, s = t & 1023;
  const int tid = threadIdx.x;
#pragma unroll
  for (int i = 0; i < 3; ++i) {
    const int idx = tid + i * 256;
    const int h = idx >> 6;
    const float2 a0 = ml0[(size_t)(b * NHEAD + h) * SEQ + s];
    const float2 a1 = ml1[(size_t)(b * NHEAD + h) * SEQ + s];
    const float mm = fmaxf(a0.x, a1.x);
    const float w0 = __expf(a0.x - mm), w1 = __expf(a1.x - mm);
    const float denom = a0.y * w0 + a1.y * w1;
    const size_t o = (size_t)t * HDIM + idx;
    const float v = (O0[o] * w0 + O1[o] * w1) / denom;
    const short hh = f2bf(v);
    Ch[o] = hh;
    Cl[o] = f2bf(v - bf2f(hh));
  }
}

// ============ transpose + f32->bf16 (expert weights) ============
__global__ __launch_bounds__(256) void transpose_to_bf16(
    const float* __restrict__ W, short* __restrict__ WT, int K, int N)
{
  const size_t off = (size_t)blockIdx.z * (size_t)K * N;
  const float* Wp = W + off;
  short* WTp = WT + off;
  __shared__ float t[32][33];
  const int tid = threadIdx.x;
  const int tx = tid & 31, ty = tid >> 5;
  const int n0 = blockIdx.x * 32, k0 = blockIdx.y * 32;
#pragma unroll
  for (int r = 0; r < 4; ++r)
    t[ty + r * 8][tx] = Wp[(size_t)(k0 + ty + r * 8) * N + n0 + tx];
  __syncthreads();
#pragma unroll
  for (int r = 0; r < 4; ++r)
    WTp[(size_t)(n0 + ty + r * 8) * K + k0 + tx] = f2bf(t[tx][ty + r * 8]);
}

// ============ expert up-proj: single-buffer (16 KB LDS), compact padded grid.
// GELU via fast tanh form (one v_exp + ~7 VALU vs erff's ~30): deviation from
// exact-erf GELU <= ~1e-3 abs, BELOW the bf16 quantization of interb (~2e-3),
// and shrinks through the 3072-term down-proj average. ============
__global__ __launch_bounds__(256) void expert_up_mfma(
    const short* __restrict__ Abf, const short* __restrict__ WiT,
    const float* __restrict__ bi, const int* __restrict__ perm,
    const int* __restrict__ offs, short* __restrict__ interb)
{
  const int row0 = blockIdx.x * 128;
  if (row0 >= offs[NEXP]) return;
  int e = 0;
  while (offs[e + 1] <= row0) ++e;
  __shared__ __align__(16) short lA[4096];
  __shared__ __align__(16) short lB[4096];
  __shared__ int toks[128];
  const int tid = threadIdx.x;
  const int w = tid >> 6, lane = tid & 63;
  const int wr = w >> 1, wc = w & 1;
  const int col0 = blockIdx.y * 128;
  if (tid < 128) toks[tid] = perm[row0 + tid];   // pads already -1
  __syncthreads();
  const int sr = lane & 15, kg = lane >> 4;
  int t0 = toks[2 * w * 16 + sr];        if (t0 < 0) t0 = toks[0];
  int t1 = toks[(2 * w + 1) * 16 + sr];  if (t1 < 0) t1 = toks[0];
  const size_t a0 = (size_t)t0 * HDIM + kg * 8;
  const size_t a1 = (size_t)t1 * HDIM + kg * 8;
  const short* Bt = WiT + (size_t)e * FDIM * HDIM;
  const size_t b0 = (size_t)(col0 + 2 * w * 16 + sr) * HDIM + kg * 8;
  const size_t b1 = b0 + (size_t)16 * HDIM;
  const int d0 = (2 * w) * 512, d1 = (2 * w + 1) * 512;
#define STAGE_E(k0) do { \
    gload16(Abf + a0 + (k0), &lA[d0]); \
    gload16(Abf + a1 + (k0), &lA[d1]); \
    gload16(Bt + b0 + (k0), &lB[d0]); \
    gload16(Bt + b1 + (k0), &lB[d1]); \
  } while (0)
  f32x4 acc[4][4] = {};
  STAGE_E(0);
  pipe_wait_barrier();
  for (int t = 0; t < 24; ++t) {
    s16x8 af[4], bg[4];
#pragma unroll
    for (int i = 0; i < 4; ++i) {
      af[i] = *(const s16x8*)&lA[(wr * 4 + i) * 512 + lane * 8];
      bg[i] = *(const s16x8*)&lB[(wc * 4 + i) * 512 + lane * 8];
    }
    __syncthreads();
    if (t < 23) STAGE_E((t + 1) * 32);
#pragma unroll
    for (int mi = 0; mi < 4; ++mi)
#pragma unroll
      for (int ni = 0; ni < 4; ++ni)
        acc[mi][ni] = __builtin_amdgcn_mfma_f32_16x16x32_bf16(af[mi], bg[ni], acc[mi][ni], 0, 0, 0);
    pipe_wait_barrier();
  }
#undef STAGE_E
  const int cl = lane & 15, rg = lane >> 4;
#pragma unroll
  for (int mi = 0; mi < 4; ++mi) {
#pragma unroll
    for (int r = 0; r < 4; ++r) {
      const int rl = wr * 64 + mi * 16 + rg * 4 + r;
      const int tok = toks[rl];
      if (tok < 0) continue;
#pragma unroll
      for (int ni = 0; ni < 4; ++ni) {
        const int c = col0 + wc * 64 + ni * 16 + cl;
        float v = acc[mi][ni][r] + bi[(size_t)e * FDIM + c];
        // gelu_tanh(v) = v * (1 - 1/(exp(2*sqrt(2/pi)*(v+0.044715 v^3)) + 1))
        // tails: ex->inf => v (pass-through); ex->0 => 0. No NaN paths.
        const float ex = __expf(v * (1.5957691216f + 0.0713548162f * v * v));
        v = v - v / (ex + 1.0f);
        interb[(size_t)tok * FDIM + c] = f2bf(v);
      }
    }
  }
}

// ============ down-proj: single-buffer (16 KB LDS), SPLIT-K x2 ============
__global__ __launch_bounds__(256) void wo_mfma(
    const short* __restrict__ Ab, const short* __restrict__ BT,
    const float* __restrict__ bias, float* __restrict__ C0, float* __restrict__ C1)
{
  __shared__ __align__(16) short lA[4096];
  __shared__ __align__(16) short lB[4096];
  const int tid = threadIdx.x;
  const int w = tid >> 6, lane = tid & 63;
  const int wr = w >> 1, wc = w & 1;
  const int row0 = blockIdx.y * 128, col0 = blockIdx.x * 128;
  const int z = blockIdx.z;
  const int kbase = z * 1536;
  const int sr = lane & 15, kg = lane >> 4;
  const size_t a0 = (size_t)(row0 + 2 * w * 16 + sr) * FDIM + kbase + kg * 8;
  const size_t a1 = a0 + (size_t)16 * FDIM;
  const size_t b0 = (size_t)(col0 + 2 * w * 16 + sr) * FDIM + kbase + kg * 8;
  const size_t b1 = b0 + (size_t)16 * FDIM;
  const int d0 = (2 * w) * 512, d1 = (2 * w + 1) * 512;
#define STAGE_W(k0) do { \
    gload16(Ab + a0 + (k0), &lA[d0]); \
    gload16(Ab + a1 + (k0), &lA[d1]); \
    gload16(BT + b0 + (k0), &lB[d0]); \
    gload16(BT + b1 + (k0), &lB[d1]); \
  } while (0)
  f32x4 acc[4][4] = {};
  STAGE_W(0);
  pipe_wait_barrier();
  for (int t = 0; t < 48; ++t) {
    s16x8 af[4], bg[4];
#pragma unroll
    for (int i = 0; i < 4; ++i) {
      af[i] = *(const s16x8*)&lA[(wr * 4 + i) * 512 + lane * 8];
      bg[i] = *(const s16x8*)&lB[(wc * 4 + i) * 512 + lane * 8];
    }
    __syncthreads();
    if (t < 47) STAGE_W((t + 1) * 32);
#pragma unroll
    for (int mi = 0; mi < 4; ++mi)
#pragma unroll
      for (int ni = 0; ni < 4; ++ni)
        acc[mi][ni] = __builtin_amdgcn_mfma_f32_16x16x32_bf16(af[mi], bg[ni], acc[mi][ni], 0, 0, 0);
    pipe_wait_barrier();
  }
#undef STAGE_W
  float* C = z ? C1 : C0;
  const int cl = lane & 15, rg = lane >> 4;
#pragma unroll
  for (int mi = 0; mi < 4; ++mi) {
#pragma unroll
    for (int r = 0; r < 4; ++r) {
      const int row = row0 + wr * 64 + mi * 16 + rg * 4 + r;
#pragma unroll
      for (int ni = 0; ni < 4; ++ni) {
        const int c = col0 + wc * 64 + ni * 16 + cl;
        C[(size_t)row * HDIM + c] = acc[mi][ni][r] + (z ? 0.f : bias[c]);
      }
    }
  }
}

// ============ two-partial add + residual + LayerNorm ============
__global__ __launch_bounds__(256) void add2_ln_kernel(
    const float* __restrict__ X1, const float* __restrict__ X2,
    const float* __restrict__ R, const float* __restrict__ g,
    const float* __restrict__ bb, float* __restrict__ out)
{
  const int t = blockIdx.x;
  const int tid = threadIdx.x;
  const float* x1 = X1 + (size_t)t * HDIM;
  const float* x2 = X2 + (size_t)t * HDIM;
  const float* r = R + (size_t)t * HDIM;
  float v[3];
  float sum = 0.f, ssq = 0.f;
#pragma unroll
  for (int i = 0; i < 3; ++i) {
    const float val = x1[tid + i * 256] + x2[tid + i * 256] + r[tid + i * 256];
    v[i] = val;
    sum += val;
    ssq += val * val;
  }
#pragma unroll
  for (int o = 32; o > 0; o >>= 1) {
    sum += __shfl_down(sum, o);
    ssq += __shfl_down(ssq, o);
  }
  __shared__ float red[10];
  const int wid = tid >> 6, lane = tid & 63;
  if (lane == 0) { red[wid] = sum; red[4 + wid] = ssq; }
  __syncthreads();
  if (tid == 0) {
    const float s = red[0] + red[1] + red[2] + red[3];
    const float q = red[4] + red[5] + red[6] + red[7];
    const float mean = s * (1.f / HDIM);
    const float var = q * (1.f / HDIM) - mean * mean;
    red[8] = mean;
    red[9] = rsqrtf(fmaxf(var, 0.f) + 1e-12f);
  }
  __syncthreads();
  const float mean = red[8], rstd = red[9];
#pragma unroll
  for (int i = 0; i < 3; ++i) {
    const int idx = tid + i * 256;
    out[(size_t)t * HDIM + idx] = g[idx] * (v[i] - mean) * rstd + bb[idx];
  }
}

// ============ LN1 variant: also emits bf16 copy (fuses convert_bf16) ============
__global__ __launch_bounds__(256) void add2_ln_bf16_kernel(
    const float* __restrict__ X1, const float* __restrict__ X2,
    const float* __restrict__ R, const float* __restrict__ g,
    const float* __restrict__ bb, float* __restrict__ out, short* __restrict__ outb)
{
  const int t = blockIdx.x;
  const int tid = threadIdx.x;
  const float* x1 = X1 + (size_t)t * HDIM;
  const float* x2 = X2 + (size_t)t * HDIM;
  const float* r = R + (size_t)t * HDIM;
  float v[3];
  float sum = 0.f, ssq = 0.f;
#pragma unroll
  for (int i = 0; i < 3; ++i) {
    const float val = x1[tid + i * 256] + x2[tid + i * 256] + r[tid + i * 256];
    v[i] = val;
    sum += val;
    ssq += val * val;
  }
#pragma unroll
  for (int o = 32; o > 0; o >>= 1) {
    sum += __shfl_down(sum, o);
    ssq += __shfl_down(ssq, o);
  }
  __shared__ float red[10];
  const int wid = tid >> 6, lane = tid & 63;
  if (lane == 0) { red[wid] = sum; red[4 + wid] = ssq; }
  __syncthreads();
  if (tid == 0) {
    const float s = red[0] + red[1] + red[2] + red[3];
    const float q = red[4] + red[5] + red[6] + red[7];
    const float mean = s * (1.f / HDIM);
    const float var = q * (1.f / HDIM) - mean * mean;
    red[8] = mean;
    red[9] = rsqrtf(fmaxf(var, 0.f) + 1e-12f);
  }
  __syncthreads();
  const float mean = red[8], rstd = red[9];
#pragma unroll
  for (int i = 0; i < 3; ++i) {
    const int idx = tid + i * 256;
    const float o = g[idx] * (v[i] - mean) * rstd + bb[idx];
    out[(size_t)t * HDIM + idx] = o;
    outb[(size_t)t * HDIM + idx] = f2bf(o);
  }
}

// ============ router (f32 — keeps argmax path bit-identical) ============
__global__ __launch_bounds__(256) void router_kernel(
    const float* __restrict__ X, const float* __restrict__ Wr,
    const float* __restrict__ br, float* __restrict__ scores_out,
    int* __restrict__ expert, int* __restrict__ counts)
{
  const int wid = threadIdx.x >> 6, lane = threadIdx.x & 63;
  const int tok = blockIdx.x * 4 + wid;
  const float* x = X + (size_t)tok * HDIM;
  float acc[8] = {};
  for (int k0 = 0; k0 < HDIM; k0 += 64) {
    const float xv = x[k0 + lane];
    const float* wrow = Wr + (size_t)(k0 + lane) * NEXP;
    const float4 w0 = *reinterpret_cast<const float4*>(wrow);
    const float4 w1 = *reinterpret_cast<const float4*>(wrow + 4);
    acc[0] = fmaf(xv, w0.x, acc[0]);
    acc[1] = fmaf(xv, w0.y, acc[1]);
    acc[2] = fmaf(xv, w0.z, acc[2]);
    acc[3] = fmaf(xv, w0.w, acc[3]);
    acc[4] = fmaf(xv, w1.x, acc[4]);
    acc[5] = fmaf(xv, w1.y, acc[5]);
    acc[6] = fmaf(xv, w1.z, acc[6]);
    acc[7] = fmaf(xv, w1.w, acc[7]);
  }
#pragma unroll
  for (int e = 0; e < 8; ++e)
#pragma unroll
    for (int o = 32; o > 0; o >>= 1) acc[e] += __shfl_down(acc[e], o);
  if (lane == 0) {
    float mx = -3.0e38f;
#pragma unroll
    for (int e = 0; e < 8; ++e) { acc[e] += br[e]; mx = fmaxf(mx, acc[e]); }
    float sum = 0.f;
#pragma unroll
    for (int e = 0; e < 8; ++e) { acc[e] = expf(acc[e] - mx); sum += acc[e]; }
    const float inv = 1.f / sum;
    int best = 0;
    float bv = acc[0];
#pragma unroll
    for (int e = 0; e < 8; ++e) {
      const float p = acc[e] * inv;
      scores_out[(size_t)tok * NEXP + e] = p;
      if (acc[e] > bv) { bv = acc[e]; best = e; }
    }
    expert[tok] = best;
    atomicAdd(&counts[best], 1);
  }
}

// padded prefix: each expert segment rounded up to a multiple of 128
__global__ void offsets_kernel(const int* __restrict__ counts, int* __restrict__ offs)
{
  if (threadIdx.x == 0 && blockIdx.x == 0) {
    int a = 0;
    for (int e = 0; e < NEXP; ++e) {
      offs[e] = a;
      a += ((counts[e] + 127) >> 7) << 7;
    }
    offs[NEXP] = a;
  }
}

__global__ __launch_bounds__(256) void scatter_kernel(
    const int* __restrict__ expert, const int* __restrict__ offs,
    int* __restrict__ cursor, int* __restrict__ perm)
{
  const int t = blockIdx.x * 256 + threadIdx.x;
  if (t >= TOKS) return;
  const int e = expert[t];
  const int pos = atomicAdd(&cursor[e], 1);
  perm[offs[e] + pos] = t;
}

extern "C" void kernel_launch(void* const* d_in, const int* in_sizes, int n_in,
                              void* d_out, int out_size, void* d_ws, size_t ws_size,
                              hipStream_t stream) {
  const float* hidden = (const float*)d_in[0];
  const float* Wq  = (const float*)d_in[1];
  const float* bq  = (const float*)d_in[2];
  const float* Wk  = (const float*)d_in[3];
  const float* bk  = (const float*)d_in[4];
  const float* Wv  = (const float*)d_in[5];
  const float* bv  = (const float*)d_in[6];
  const float* Wao = (const float*)d_in[7];
  const float* bao = (const float*)d_in[8];
  const float* ln1g = (const float*)d_in[9];
  const float* ln1b = (const float*)d_in[10];
  const float* Wr  = (const float*)d_in[11];
  const float* br  = (const float*)d_in[12];
  const float* Wi  = (const float*)d_in[13];
  const float* bi  = (const float*)d_in[14];
  const float* Wo  = (const float*)d_in[15];
  const float* bo  = (const float*)d_in[16];
  const float* ln2g = (const float*)d_in[17];
  const float* ln2b = (const float*)d_in[18];

  float* out = (float*)d_out;
  float* scores_out = out + (size_t)TOKS * HDIM;

  const size_t M1 = (size_t)TOKS * HDIM;     // 6.29M floats
  const size_t HW = (size_t)HDIM * HDIM;
  float* ws = (float*)d_ws;
  // ---- arena (float offsets, by liveness) ----
  short* QKhb = (short*)ws;
  short* QKlb = (short*)(ws + M1);
  short* VThb = (short*)(ws + 2 * M1);
  short* VTlb = VThb + (size_t)BATCH * NHEAD * 64 * 1024;
  float* O0b  = ws + 3 * M1;
  float* O1b  = ws + 4 * M1;
  float* bqkv = ws + 3 * M1;                 // dead before attention writes O0
  short* Hh = (short*)(ws + 4 * M1);
  short* Hl = Hh + M1;
  short* Ch = (short*)(ws + 2 * M1);         // ctx split (VT region, dead after attention)
  short* Cl = Ch + M1;
  short* wt = (short*)(ws + 5 * M1);
  short* WqkvhT = wt;
  short* WqkvlT = wt + 3 * HW;
  short* WaohT  = wt + 6 * HW;
  short* WaolT  = wt + 7 * HW;
  float2* ml0 = (float2*)(ws + 5 * M1 + 4 * HW);
  float2* ml1 = ml0 + (size_t)BATCH * NHEAD * SEQ;
  float* aoproj0  = ws;                      // QKhb region (dead after attention)
  float* aoproj1  = ws + 3 * M1;             // O0 region (dead after combine)
  float* attn_out = ws + M1;                 // QKlb region
  float* tmp2a    = ws;
  float* tmp2b    = ws + 3 * M1;
  short* Abf    = (short*)(ws + 2 * M1);     // expert phase (Ch/Cl dead after AO)
  short* WiT    = Abf + M1;
  short* WoT    = WiT + (size_t)NEXP * FDIM * HDIM;
  short* interb = WoT + (size_t)HDIM * FDIM;
  int* ints   = (int*)(interb + (size_t)TOKS * FDIM);
  int* perm   = ints;                        // PERMSZ (padded)
  int* expert = ints + PERMSZ;
  int* counts = expert + TOKS;
  int* offs   = counts + NEXP;               // NEXP+1 padded prefix
  int* cursor = offs + NEXP + 1;

  hipMemsetAsync(counts, 0, (NEXP + NEXP + 1 + NEXP) * sizeof(int), stream);
  hipMemsetAsync(perm, 0xFF, PERMSZ * sizeof(int), stream);   // pads = -1
  hipMemcpyAsync(bqkv,        bq, HDIM * sizeof(float), hipMemcpyDeviceToDevice, stream);
  hipMemcpyAsync(bqkv + 768,  bk, HDIM * sizeof(float), hipMemcpyDeviceToDevice, stream);
  hipMemcpyAsync(bqkv + 1536, bv, HDIM * sizeof(float), hipMemcpyDeviceToDevice, stream);

  const dim3 blk(256);
  // --- split prep ---
  convert_split<<<dim3(TOKS * HDIM / 4 / 256), blk, 0, stream>>>(hidden, Hh, Hl, TOKS * HDIM / 4);
  transpose_split<<<dim3(24, 24), blk, 0, stream>>>(Wq,  WqkvhT,          WqkvlT,          HDIM, HDIM);
  transpose_split<<<dim3(24, 24), blk, 0, stream>>>(Wk,  WqkvhT + HW,     WqkvlT + HW,     HDIM, HDIM);
  transpose_split<<<dim3(24, 24), blk, 0, stream>>>(Wv,  WqkvhT + 2 * HW, WqkvlT + 2 * HW, HDIM, HDIM);
  transpose_split<<<dim3(24, 24), blk, 0, stream>>>(Wao, WaohT,           WaolT,           HDIM, HDIM);

  // --- fused QKV projection (depth-2 counted-vmcnt pipeline + XCD swizzle) ---
  qkv_split_mfma<<<dim3(2304 / 128, TOKS / 128), blk, 0, stream>>>(
      Hh, Hl, WqkvhT, WqkvlT, bqkv, QKhb, QKlb, VThb, VTlb);

  // --- MFMA flash attention (bf16 P, Kh-only QK), KV-split x2, 2-wave blocks ---
  attention_part<<<dim3((SEQ / 64) * 2, NHEAD, BATCH), dim3(128), 0, stream>>>(
      QKhb, QKlb, VThb, VTlb, O0b, O1b, ml0, ml1);
  combine_split<<<dim3(TOKS), blk, 0, stream>>>(O0b, O1b, ml0, ml1, Ch, Cl);

  // --- AO projection (single-buf 32KB, split-K x2) + LN1 (fused bf16 emit -> Abf) ---
  gemm_splitk_staged<<<dim3(HDIM / 128, TOKS / 128, 2), blk, 0, stream>>>(
      Ch, Cl, WaohT, WaolT, bao, aoproj0, aoproj1, HDIM, HDIM);
  add2_ln_bf16_kernel<<<dim3(TOKS), blk, 0, stream>>>(
      aoproj0, aoproj1, hidden, ln1g, ln1b, attn_out, Abf);

  // --- router + dispatch (padded permutation) ---
  router_kernel<<<dim3(TOKS / 4), blk, 0, stream>>>(attn_out, Wr, br, scores_out, expert, counts);
  offsets_kernel<<<dim3(1), dim3(64), 0, stream>>>(counts, offs);
  scatter_kernel<<<dim3(TOKS / 256), blk, 0, stream>>>(expert, offs, cursor, perm);

  // --- expert FFN (single-buf 16KB kernels; fast-tanh GELU; split-K down-proj) ---
  transpose_to_bf16<<<dim3(FDIM / 32, HDIM / 32, NEXP), blk, 0, stream>>>(Wi, WiT, HDIM, FDIM);
  transpose_to_bf16<<<dim3(HDIM / 32, FDIM / 32, 1), blk, 0, stream>>>(Wo, WoT, FDIM, HDIM);

  expert_up_mfma<<<dim3(PERMSZ / 128, FDIM / 128), blk, 0, stream>>>(
      Abf, WiT, bi, perm, offs, interb);
  wo_mfma<<<dim3(HDIM / 128, TOKS / 128, 2), blk, 0, stream>>>(interb, WoT, bo, tmp2a, tmp2b);
  add2_ln_kernel<<<dim3(TOKS), blk, 0, stream>>>(tmp2a, tmp2b, attn_out, ln2g, ln2b, out);
}

// Round 27
// 763.324 us; speedup vs baseline: 1.0902x; 1.0138x over previous
//
#include <hip/hip_runtime.h>
#include <math.h>
#include <stdint.h>

#define TOKS 8192
#define HDIM 768
#define FDIM 3072
#define NEXP 8
#define NHEAD 12
#define SEQ 1024
#define BATCH 8
#define PERMSZ 9216   // 8192 + 8*128 worst-case padding

typedef __attribute__((ext_vector_type(8))) short s16x8;   // 8 bf16 = 4 VGPR
typedef __attribute__((ext_vector_type(4))) short s16x4;
typedef __attribute__((ext_vector_type(4))) float f32x4;

__device__ __forceinline__ short f2bf(float f) {
  uint32_t u = __float_as_uint(f);
  uint32_t r = (u + 0x7fffu + ((u >> 16) & 1u)) >> 16;   // RTN-even
  return (short)(r & 0xffffu);
}
__device__ __forceinline__ float bf2f(short h) {
  return __uint_as_float(((uint32_t)(uint16_t)h) << 16);
}
__device__ __forceinline__ void gload16(const void* g, void* l) {
  __builtin_amdgcn_global_load_lds(
      (const __attribute__((address_space(1))) uint32_t*)g,
      (__attribute__((address_space(3))) uint32_t*)l, 16, 0, 0);
}
// drain outstanding global->LDS DMA, then workgroup barrier.
__device__ __forceinline__ void pipe_wait_barrier() {
  asm volatile("s_waitcnt vmcnt(0)" ::: "memory");
  __builtin_amdgcn_s_barrier();
}
// LDS-reads-retired fence + raw barrier (no vmcnt drain — keeps DMA in flight).
__device__ __forceinline__ void lds_read_barrier() {
  asm volatile("s_waitcnt lgkmcnt(0)" ::: "memory");
  __builtin_amdgcn_s_barrier();
}

// ============ f32 -> (hi,lo) bf16 split, 4 elems/thread ============
__global__ __launch_bounds__(256) void convert_split(
    const float* __restrict__ X, short* __restrict__ Xh, short* __restrict__ Xl, int n4)
{
  const int i = blockIdx.x * 256 + threadIdx.x;
  if (i >= n4) return;
  const float4 v = ((const float4*)X)[i];
  const float a[4] = {v.x, v.y, v.z, v.w};
  s16x4 h, l;
#pragma unroll
  for (int j = 0; j < 4; ++j) {
    h[j] = f2bf(a[j]);
    l[j] = f2bf(a[j] - bf2f(h[j]));
  }
  ((s16x4*)Xh)[i] = h;
  ((s16x4*)Xl)[i] = l;
}

// ============ transpose + split: WT{h,l}[n][k] = split(W[k][n]) ============
__global__ __launch_bounds__(256) void transpose_split(
    const float* __restrict__ W, short* __restrict__ WTh, short* __restrict__ WTl,
    int K, int N)
{
  __shared__ float t[32][33];
  const int tid = threadIdx.x;
  const int tx = tid & 31, ty = tid >> 5;
  const int n0 = blockIdx.x * 32, k0 = blockIdx.y * 32;
#pragma unroll
  for (int r = 0; r < 4; ++r)
    t[ty + r * 8][tx] = W[(size_t)(k0 + ty + r * 8) * N + n0 + tx];
  __syncthreads();
#pragma unroll
  for (int r = 0; r < 4; ++r) {
    const float v = t[tx][ty + r * 8];
    const short h = f2bf(v);
    WTh[(size_t)(n0 + ty + r * 8) * K + k0 + tx] = h;
    WTl[(size_t)(n0 + ty + r * 8) * K + k0 + tx] = f2bf(v - bf2f(h));
  }
}

// ============ QKV split-GEMM: depth-2 counted-vmcnt pipeline (64 KB LDS),
// raw barriers (no vmcnt drain mid-loop); XCD-swizzled grid; Q pre-scaled 1/8. ====
__global__ __launch_bounds__(256) void qkv_split_mfma(
    const short* __restrict__ Ah, const short* __restrict__ Al,
    const short* __restrict__ BhT, const short* __restrict__ BlT,
    const float* __restrict__ bias,
    short* __restrict__ QKh, short* __restrict__ QKl,
    short* __restrict__ VTh, short* __restrict__ VTl)
{
  const int K = 768;
  __shared__ __align__(16) short lAh[2][4096];
  __shared__ __align__(16) short lAl[2][4096];
  __shared__ __align__(16) short lBh[2][4096];
  __shared__ __align__(16) short lBl[2][4096];
  // XCD swizzle: nwg = 18*64 = 1152, chunk = 144 per XCD (bijective)
  const int dsp = blockIdx.x + 18 * blockIdx.y;
  const int orig = (dsp & 7) * 144 + (dsp >> 3);
  const int bx = orig % 18, by = orig / 18;
  const int tid = threadIdx.x;
  const int w = tid >> 6, lane = tid & 63;
  const int wr = w >> 1, wc = w & 1;
  const int row0 = by * 128, col0 = bx * 128;
  const int sr = lane & 15, kg = lane >> 4;
  const size_t a0 = (size_t)(row0 + 2 * w * 16 + sr) * K + kg * 8;
  const size_t a1 = a0 + (size_t)16 * K;
  const size_t b0 = (size_t)(col0 + 2 * w * 16 + sr) * K + kg * 8;
  const size_t b1 = b0 + (size_t)16 * K;
  const int d0 = (2 * w) * 512, d1 = (2 * w + 1) * 512;
#define STAGE_Q(bu, k0) do { \
    gload16(Ah + a0 + (k0), &lAh[bu][d0]); \
    gload16(Ah + a1 + (k0), &lAh[bu][d1]); \
    gload16(Al + a0 + (k0), &lAl[bu][d0]); \
    gload16(Al + a1 + (k0), &lAl[bu][d1]); \
    gload16(BhT + b0 + (k0), &lBh[bu][d0]); \
    gload16(BhT + b1 + (k0), &lBh[bu][d1]); \
    gload16(BlT + b0 + (k0), &lBl[bu][d0]); \
    gload16(BlT + b1 + (k0), &lBl[bu][d1]); \
  } while (0)
  f32x4 acc[4][4] = {};
  STAGE_Q(0, 0);
  STAGE_Q(1, 32);
  asm volatile("s_waitcnt vmcnt(8)" ::: "memory");   // stage(0) landed; stage(1) in flight
  __builtin_amdgcn_s_barrier();
  for (int t = 0; t < 24; ++t) {
    const int cur = t & 1;
    s16x8 ah[4], al[4], bh[4], bl[4];
#pragma unroll
    for (int i = 0; i < 4; ++i) {
      ah[i] = *(const s16x8*)&lAh[cur][(wr * 4 + i) * 512 + lane * 8];
      al[i] = *(const s16x8*)&lAl[cur][(wr * 4 + i) * 512 + lane * 8];
      bh[i] = *(const s16x8*)&lBh[cur][(wc * 4 + i) * 512 + lane * 8];
      bl[i] = *(const s16x8*)&lBl[cur][(wc * 4 + i) * 512 + lane * 8];
    }
    lds_read_barrier();   // reads retired; buf[cur] free (DMA stays in flight!)
    if (t + 2 < 24) STAGE_Q(cur, (t + 2) * 32);   // depth-2 prefetch into freed buffer
#pragma unroll
    for (int mi = 0; mi < 4; ++mi)
#pragma unroll
      for (int ni = 0; ni < 4; ++ni) {
        acc[mi][ni] = __builtin_amdgcn_mfma_f32_16x16x32_bf16(ah[mi], bh[ni], acc[mi][ni], 0, 0, 0);
        acc[mi][ni] = __builtin_amdgcn_mfma_f32_16x16x32_bf16(ah[mi], bl[ni], acc[mi][ni], 0, 0, 0);
        acc[mi][ni] = __builtin_amdgcn_mfma_f32_16x16x32_bf16(al[mi], bh[ni], acc[mi][ni], 0, 0, 0);
      }
    // counted wait: stage(t+1) done, stage(t+2)'s 8 loads remain outstanding
    if (t + 2 < 24) asm volatile("s_waitcnt vmcnt(8)" ::: "memory");
    else            asm volatile("s_waitcnt vmcnt(0)" ::: "memory");
    __builtin_amdgcn_s_barrier();
  }
#undef STAGE_Q
  const int cl = lane & 15, rg = lane >> 4;
#pragma unroll
  for (int mi = 0; mi < 4; ++mi)
#pragma unroll
    for (int ni = 0; ni < 4; ++ni) {
      const int c = col0 + wc * 64 + ni * 16 + cl;
      const int rowb = row0 + wr * 64 + mi * 16 + rg * 4;
      // Q columns (c<768) pre-scaled by 1/8: exact power-of-2, commutes through
      // the bf16 split and the QK^T MFMA bit-exactly.
      const float qscale = (c < 768) ? 0.125f : 1.0f;
      s16x4 hv, lv;
#pragma unroll
      for (int r = 0; r < 4; ++r) {
        const float v = (acc[mi][ni][r] + bias[c]) * qscale;
        const short hh = f2bf(v);
        hv[r] = hh;
        lv[r] = f2bf(v - bf2f(hh));
      }
      if (c < 1536) {
#pragma unroll
        for (int r = 0; r < 4; ++r) {
          QKh[(size_t)(rowb + r) * 1536 + c] = hv[r];
          QKl[(size_t)(rowb + r) * 1536 + c] = lv[r];
        }
      } else {          // V column: transposed store VT[b][h][d][s]
        const int dall = c - 1536;
        const size_t vi = (((size_t)((rowb >> 10) * NHEAD + (dall >> 6))) * 64 + (dall & 63)) * 1024
                          + (rowb & 1023);
        *(s16x4*)(VTh + vi) = hv;
        *(s16x4*)(VTl + vi) = lv;
      }
    }
}

// ============ AO GEMM: single-buffer split-bf16 (32 KB LDS), SPLIT-K x2
// (NT=12 too short for depth-2 — measured regression in R24) ============
__global__ __launch_bounds__(256) void gemm_splitk_staged(
    const short* __restrict__ Ah, const short* __restrict__ Al,
    const short* __restrict__ BhT, const short* __restrict__ BlT,
    const float* __restrict__ bias, float* __restrict__ C0, float* __restrict__ C1,
    int N, int K)
{
  __shared__ __align__(16) short lAh[4096];
  __shared__ __align__(16) short lAl[4096];
  __shared__ __align__(16) short lBh[4096];
  __shared__ __align__(16) short lBl[4096];
  const int tid = threadIdx.x;
  const int w = tid >> 6, lane = tid & 63;
  const int wr = w >> 1, wc = w & 1;
  const int row0 = blockIdx.y * 128, col0 = blockIdx.x * 128;
  const int z = blockIdx.z;
  const int Khalf = K >> 1, koff = z * Khalf;
  const int sr = lane & 15, kg = lane >> 4;
  const size_t a0 = (size_t)(row0 + 2 * w * 16 + sr) * K + koff + kg * 8;
  const size_t a1 = a0 + (size_t)16 * K;
  const size_t b0 = (size_t)(col0 + 2 * w * 16 + sr) * K + koff + kg * 8;
  const size_t b1 = b0 + (size_t)16 * K;
  const int d0 = (2 * w) * 512, d1 = (2 * w + 1) * 512;
#define STAGE_K4(k0) do { \
    gload16(Ah + a0 + (k0), &lAh[d0]); \
    gload16(Ah + a1 + (k0), &lAh[d1]); \
    gload16(Al + a0 + (k0), &lAl[d0]); \
    gload16(Al + a1 + (k0), &lAl[d1]); \
    gload16(BhT + b0 + (k0), &lBh[d0]); \
    gload16(BhT + b1 + (k0), &lBh[d1]); \
    gload16(BlT + b0 + (k0), &lBl[d0]); \
    gload16(BlT + b1 + (k0), &lBl[d1]); \
  } while (0)
  f32x4 acc[4][4] = {};
  const int NT = Khalf >> 5;
  STAGE_K4(0);
  pipe_wait_barrier();
  for (int t = 0; t < NT; ++t) {
    s16x8 ah[4], al[4], bh[4], bl[4];
#pragma unroll
    for (int i = 0; i < 4; ++i) {
      ah[i] = *(const s16x8*)&lAh[(wr * 4 + i) * 512 + lane * 8];
      al[i] = *(const s16x8*)&lAl[(wr * 4 + i) * 512 + lane * 8];
      bh[i] = *(const s16x8*)&lBh[(wc * 4 + i) * 512 + lane * 8];
      bl[i] = *(const s16x8*)&lBl[(wc * 4 + i) * 512 + lane * 8];
    }
    __syncthreads();
    if (t + 1 < NT) STAGE_K4((t + 1) * 32);
#pragma unroll
    for (int mi = 0; mi < 4; ++mi)
#pragma unroll
      for (int ni = 0; ni < 4; ++ni) {
        acc[mi][ni] = __builtin_amdgcn_mfma_f32_16x16x32_bf16(ah[mi], bh[ni], acc[mi][ni], 0, 0, 0);
        acc[mi][ni] = __builtin_amdgcn_mfma_f32_16x16x32_bf16(ah[mi], bl[ni], acc[mi][ni], 0, 0, 0);
        acc[mi][ni] = __builtin_amdgcn_mfma_f32_16x16x32_bf16(al[mi], bh[ni], acc[mi][ni], 0, 0, 0);
      }
    pipe_wait_barrier();
  }
#undef STAGE_K4
  float* C = z ? C1 : C0;
  const int cl = lane & 15, rg = lane >> 4;
#pragma unroll
  for (int mi = 0; mi < 4; ++mi)
#pragma unroll
    for (int r = 0; r < 4; ++r) {
      const int row = row0 + wr * 64 + mi * 16 + rg * 4 + r;
#pragma unroll
      for (int ni = 0; ni < 4; ++ni) {
        const int c = col0 + wc * 64 + ni * 16 + cl;
        C[(size_t)row * N + c] = acc[mi][ni][r] + (z ? 0.f : bias[c]);
      }
    }
}

// ============ MFMA flash attention, KV-SPLIT x2 — TWO-WAVE blocks (10 KB LDS) ============
// P plain bf16; QK^T uses (Qh+Ql)*Kh only (Kl dropped: S err ~3e-3 abs, averaged to
// ~1e-4 in O by softmax over ~900 keys — router-safe class, same as bf16-P change).
__global__ __launch_bounds__(128, 2) void attention_part(
    const short* __restrict__ QKh, const short* __restrict__ QKl,
    const short* __restrict__ VTh, const short* __restrict__ VTl,
    float* __restrict__ O0, float* __restrict__ O1,
    float2* __restrict__ ml0, float2* __restrict__ ml1)
{
  __shared__ __align__(16) short lPh[2][2560];   // [wave][(mi*2+ks2)*640 + q*40 + koff]
  const int tid = threadIdx.x;
  const int w = tid >> 6, lane = tid & 63;
  // XCD swizzle: nwg = 32*12*8 = 3072, chunk = 384 (= one batch per XCD)
  const int dsp = blockIdx.x + 32 * (blockIdx.y + 12 * blockIdx.z);
  const int orig = (dsp & 7) * 384 + (dsp >> 3);
  const int wx = orig & 31;
  const int b = orig / 384, h = (orig >> 5) % 12;
  const int z = wx & 1;
  const int q0 = (wx >> 1) * 64 + w * 32;    // this wave's 32 q-rows
  const int kv0 = z * 512;
  const int sr = lane & 15, kg = lane >> 4;
  const int cl = sr, rg = kg;
  short* myPh = lPh[w];
  float* Op = z ? O1 : O0;
  float2* mlp = z ? ml1 : ml0;

  s16x8 qh[2][2], ql[2][2];
  {
    const size_t qbase = ((size_t)b * SEQ + q0 + sr) * 1536 + h * 64 + kg * 8;
#pragma unroll
    for (int mi = 0; mi < 2; ++mi)
#pragma unroll
      for (int ks = 0; ks < 2; ++ks) {
        const size_t o = qbase + (size_t)mi * (16 * 1536) + ks * 32;
        qh[mi][ks] = *(const s16x8*)(QKh + o);
        ql[mi][ks] = *(const s16x8*)(QKl + o);
      }
  }
  float m_run[2][4], l_run[2][4];
#pragma unroll
  for (int mi = 0; mi < 2; ++mi)
#pragma unroll
    for (int r = 0; r < 4; ++r) { m_run[mi][r] = -3.0e38f; l_run[mi][r] = 0.f; }
  f32x4 acc_o[2][4] = {};

  for (int kt = kv0; kt < kv0 + 512; kt += 64) {
    s16x8 kh[4][2];
    {
      const size_t kbase = ((size_t)b * SEQ + kt + sr) * 1536 + 768 + h * 64 + kg * 8;
#pragma unroll
      for (int ni = 0; ni < 4; ++ni)
#pragma unroll
        for (int ks = 0; ks < 2; ++ks) {
          const size_t o = kbase + (size_t)ni * (16 * 1536) + ks * 32;
          kh[ni][ks] = *(const s16x8*)(QKh + o);
        }
    }
    f32x4 accs[2][4] = {};
    __builtin_amdgcn_s_setprio(1);
#pragma unroll
    for (int ks = 0; ks < 2; ++ks)
#pragma unroll
      for (int ni = 0; ni < 4; ++ni)
#pragma unroll
        for (int mi = 0; mi < 2; ++mi) {
          accs[mi][ni] = __builtin_amdgcn_mfma_f32_16x16x32_bf16(qh[mi][ks], kh[ni][ks], accs[mi][ni], 0, 0, 0);
          accs[mi][ni] = __builtin_amdgcn_mfma_f32_16x16x32_bf16(ql[mi][ks], kh[ni][ks], accs[mi][ni], 0, 0, 0);
        }
    __builtin_amdgcn_s_setprio(0);
    s16x8 vh[4][2], vl2[4][2];
    {
      const size_t vbase = (((size_t)(b * NHEAD + h)) * 64 + sr) * 1024 + kt + kg * 8;
#pragma unroll
      for (int nd = 0; nd < 4; ++nd)
#pragma unroll
        for (int ks2 = 0; ks2 < 2; ++ks2) {
          const size_t o = vbase + (size_t)nd * (16 * 1024) + ks2 * 32;
          vh[nd][ks2] = *(const s16x8*)(VTh + o);
          vl2[nd][ks2] = *(const s16x8*)(VTl + o);
        }
    }
#pragma unroll
    for (int mi = 0; mi < 2; ++mi)
#pragma unroll
      for (int r = 0; r < 4; ++r) {
        float mx = fmaxf(fmaxf(accs[mi][0][r], accs[mi][1][r]),
                         fmaxf(accs[mi][2][r], accs[mi][3][r]));
        mx = fmaxf(mx, __shfl_xor(mx, 1));
        mx = fmaxf(mx, __shfl_xor(mx, 2));
        mx = fmaxf(mx, __shfl_xor(mx, 4));
        mx = fmaxf(mx, __shfl_xor(mx, 8));
        const float mn = fmaxf(m_run[mi][r], mx);
        const float c = __expf(m_run[mi][r] - mn);
        m_run[mi][r] = mn;
        l_run[mi][r] *= c;
#pragma unroll
        for (int nd = 0; nd < 4; ++nd) acc_o[mi][nd][r] *= c;
        float sum = 0.f;
#pragma unroll
        for (int ni = 0; ni < 4; ++ni) {
          const float p = __expf(accs[mi][ni][r] - mn);
          const short hh = f2bf(p);
          sum += bf2f(hh);   // consistent with PV numerator (rounded P)
          const int idx = (mi * 2 + (ni >> 1)) * 640 + (rg * 4 + r) * 40 + (ni & 1) * 16 + cl;
          myPh[idx] = hh;
        }
        sum += __shfl_xor(sum, 1);
        sum += __shfl_xor(sum, 2);
        sum += __shfl_xor(sum, 4);
        sum += __shfl_xor(sum, 8);
        l_run[mi][r] += sum;
      }
    __builtin_amdgcn_s_setprio(1);
#pragma unroll
    for (int ks2 = 0; ks2 < 2; ++ks2) {
      s16x8 pf[2];
#pragma unroll
      for (int mi = 0; mi < 2; ++mi) {
        const int ra = (mi * 2 + ks2) * 640 + sr * 40 + kg * 8;
        pf[mi] = *(const s16x8*)&myPh[ra];
      }
#pragma unroll
      for (int nd = 0; nd < 4; ++nd)
#pragma unroll
        for (int mi = 0; mi < 2; ++mi) {
          acc_o[mi][nd] = __builtin_amdgcn_mfma_f32_16x16x32_bf16(pf[mi], vh[nd][ks2], acc_o[mi][nd], 0, 0, 0);
          acc_o[mi][nd] = __builtin_amdgcn_mfma_f32_16x16x32_bf16(pf[mi], vl2[nd][ks2], acc_o[mi][nd], 0, 0, 0);
        }
    }
    __builtin_amdgcn_s_setprio(0);
  }
#pragma unroll
  for (int mi = 0; mi < 2; ++mi)
#pragma unroll
    for (int nd = 0; nd < 4; ++nd)
#pragma unroll
      for (int r = 0; r < 4; ++r) {
        const int row = q0 + mi * 16 + rg * 4 + r;
        const int d = h * 64 + nd * 16 + cl;
        Op[((size_t)b * SEQ + row) * HDIM + d] = acc_o[mi][nd][r];
      }
  if (sr == 0) {
#pragma unroll
    for (int mi = 0; mi < 2; ++mi)
#pragma unroll
      for (int r = 0; r < 4; ++r) {
        const int row = q0 + mi * 16 + rg * 4 + r;
        mlp[(size_t)(b * NHEAD + h) * SEQ + row] = make_float2(m_run[mi][r], l_run[mi][r]);
      }
  }
}

// ============ combine two KV-half partials -> split-bf16 ctx (fused) ============
__global__ __launch_bounds__(256) void combine_split(
    const float* __restrict__ O0, const float* __restrict__ O1,
    const float2* __restrict__ ml0, const float2* __restrict__ ml1,
    short* __restrict__ Ch, short* __restrict__ Cl)
{
  const int t = blockIdx.x;
  const int b = t >> 10, s = t & 1023;
  const int tid = threadIdx.x;
#pragma unroll
  for (int i = 0; i < 3; ++i) {
    const int idx = tid + i * 256;
    const int h = idx >> 6;
    const float2 a0 = ml0[(size_t)(b * NHEAD + h) * SEQ + s];
    const float2 a1 = ml1[(size_t)(b * NHEAD + h) * SEQ + s];
    const float mm = fmaxf(a0.x, a1.x);
    const float w0 = __expf(a0.x - mm), w1 = __expf(a1.x - mm);
    const float denom = a0.y * w0 + a1.y * w1;
    const size_t o = (size_t)t * HDIM + idx;
    const float v = (O0[o] * w0 + O1[o] * w1) / denom;
    const short hh = f2bf(v);
    Ch[o] = hh;
    Cl[o] = f2bf(v - bf2f(hh));
  }
}

// ============ transpose + f32->bf16 (expert weights) ============
__global__ __launch_bounds__(256) void transpose_to_bf16(
    const float* __restrict__ W, short* __restrict__ WT, int K, int N)
{
  const size_t off = (size_t)blockIdx.z * (size_t)K * N;
  const float* Wp = W + off;
  short* WTp = WT + off;
  __shared__ float t[32][33];
  const int tid = threadIdx.x;
  const int tx = tid & 31, ty = tid >> 5;
  const int n0 = blockIdx.x * 32, k0 = blockIdx.y * 32;
#pragma unroll
  for (int r = 0; r < 4; ++r)
    t[ty + r * 8][tx] = Wp[(size_t)(k0 + ty + r * 8) * N + n0 + tx];
  __syncthreads();
#pragma unroll
  for (int r = 0; r < 4; ++r)
    WTp[(size_t)(n0 + ty + r * 8) * K + k0 + tx] = f2bf(t[tx][ty + r * 8]);
}

// ============ expert up-proj: depth-2 counted-vmcnt (33 KB LDS), compact grid.
// (R24 measured this loop FASTER than single-buffer: 161.8 vs 170-172 us —
// the R25 blanket revert was a misattribution.) Fast tanh-GELU epilogue. ============
__global__ __launch_bounds__(256) void expert_up_mfma(
    const short* __restrict__ Abf, const short* __restrict__ WiT,
    const float* __restrict__ bi, const int* __restrict__ perm,
    const int* __restrict__ offs, short* __restrict__ interb)
{
  const int row0 = blockIdx.x * 128;
  if (row0 >= offs[NEXP]) return;
  int e = 0;
  while (offs[e + 1] <= row0) ++e;
  __shared__ __align__(16) short lA[2][4096];
  __shared__ __align__(16) short lB[2][4096];
  __shared__ int toks[128];
  const int tid = threadIdx.x;
  const int w = tid >> 6, lane = tid & 63;
  const int wr = w >> 1, wc = w & 1;
  const int col0 = blockIdx.y * 128;
  if (tid < 128) toks[tid] = perm[row0 + tid];   // pads already -1
  __syncthreads();
  const int sr = lane & 15, kg = lane >> 4;
  int t0 = toks[2 * w * 16 + sr];        if (t0 < 0) t0 = toks[0];
  int t1 = toks[(2 * w + 1) * 16 + sr];  if (t1 < 0) t1 = toks[0];
  const size_t a0 = (size_t)t0 * HDIM + kg * 8;
  const size_t a1 = (size_t)t1 * HDIM + kg * 8;
  const short* Bt = WiT + (size_t)e * FDIM * HDIM;
  const size_t b0 = (size_t)(col0 + 2 * w * 16 + sr) * HDIM + kg * 8;
  const size_t b1 = b0 + (size_t)16 * HDIM;
  const int d0 = (2 * w) * 512, d1 = (2 * w + 1) * 512;
#define STAGE_E(bu, k0) do { \
    gload16(Abf + a0 + (k0), &lA[bu][d0]); \
    gload16(Abf + a1 + (k0), &lA[bu][d1]); \
    gload16(Bt + b0 + (k0), &lB[bu][d0]); \
    gload16(Bt + b1 + (k0), &lB[bu][d1]); \
  } while (0)
  f32x4 acc[4][4] = {};
  STAGE_E(0, 0);
  STAGE_E(1, 32);
  asm volatile("s_waitcnt vmcnt(4)" ::: "memory");
  __builtin_amdgcn_s_barrier();
  for (int t = 0; t < 24; ++t) {
    const int cur = t & 1;
    s16x8 af[4], bg[4];
#pragma unroll
    for (int i = 0; i < 4; ++i) {
      af[i] = *(const s16x8*)&lA[cur][(wr * 4 + i) * 512 + lane * 8];
      bg[i] = *(const s16x8*)&lB[cur][(wc * 4 + i) * 512 + lane * 8];
    }
    lds_read_barrier();
    if (t + 2 < 24) STAGE_E(cur, (t + 2) * 32);
#pragma unroll
    for (int mi = 0; mi < 4; ++mi)
#pragma unroll
      for (int ni = 0; ni < 4; ++ni)
        acc[mi][ni] = __builtin_amdgcn_mfma_f32_16x16x32_bf16(af[mi], bg[ni], acc[mi][ni], 0, 0, 0);
    if (t + 2 < 24) asm volatile("s_waitcnt vmcnt(4)" ::: "memory");
    else            asm volatile("s_waitcnt vmcnt(0)" ::: "memory");
    __builtin_amdgcn_s_barrier();
  }
#undef STAGE_E
  const int cl = lane & 15, rg = lane >> 4;
#pragma unroll
  for (int mi = 0; mi < 4; ++mi) {
#pragma unroll
    for (int r = 0; r < 4; ++r) {
      const int rl = wr * 64 + mi * 16 + rg * 4 + r;
      const int tok = toks[rl];
      if (tok < 0) continue;
#pragma unroll
      for (int ni = 0; ni < 4; ++ni) {
        const int c = col0 + wc * 64 + ni * 16 + cl;
        float v = acc[mi][ni][r] + bi[(size_t)e * FDIM + c];
        // gelu_tanh(v) = v * (1 - 1/(exp(2*sqrt(2/pi)*(v+0.044715 v^3)) + 1))
        const float ex = __expf(v * (1.5957691216f + 0.0713548162f * v * v));
        v = v - v / (ex + 1.0f);
        interb[(size_t)tok * FDIM + c] = f2bf(v);
      }
    }
  }
}

// ============ down-proj: depth-2 counted-vmcnt (32 KB LDS), SPLIT-K x2.
// 48-step loop — longest in the pipeline; qkv/expert_up long-loop pattern. ============
__global__ __launch_bounds__(256) void wo_mfma(
    const short* __restrict__ Ab, const short* __restrict__ BT,
    const float* __restrict__ bias, float* __restrict__ C0, float* __restrict__ C1)
{
  __shared__ __align__(16) short lA[2][4096];
  __shared__ __align__(16) short lB[2][4096];
  const int tid = threadIdx.x;
  const int w = tid >> 6, lane = tid & 63;
  const int wr = w >> 1, wc = w & 1;
  const int row0 = blockIdx.y * 128, col0 = blockIdx.x * 128;
  const int z = blockIdx.z;
  const int kbase = z * 1536;
  const int sr = lane & 15, kg = lane >> 4;
  const size_t a0 = (size_t)(row0 + 2 * w * 16 + sr) * FDIM + kbase + kg * 8;
  const size_t a1 = a0 + (size_t)16 * FDIM;
  const size_t b0 = (size_t)(col0 + 2 * w * 16 + sr) * FDIM + kbase + kg * 8;
  const size_t b1 = b0 + (size_t)16 * FDIM;
  const int d0 = (2 * w) * 512, d1 = (2 * w + 1) * 512;
#define STAGE_W(bu, k0) do { \
    gload16(Ab + a0 + (k0), &lA[bu][d0]); \
    gload16(Ab + a1 + (k0), &lA[bu][d1]); \
    gload16(BT + b0 + (k0), &lB[bu][d0]); \
    gload16(BT + b1 + (k0), &lB[bu][d1]); \
  } while (0)
  f32x4 acc[4][4] = {};
  STAGE_W(0, 0);
  STAGE_W(1, 32);
  asm volatile("s_waitcnt vmcnt(4)" ::: "memory");
  __builtin_amdgcn_s_barrier();
  for (int t = 0; t < 48; ++t) {
    const int cur = t & 1;
    s16x8 af[4], bg[4];
#pragma unroll
    for (int i = 0; i < 4; ++i) {
      af[i] = *(const s16x8*)&lA[cur][(wr * 4 + i) * 512 + lane * 8];
      bg[i] = *(const s16x8*)&lB[cur][(wc * 4 + i) * 512 + lane * 8];
    }
    lds_read_barrier();
    if (t + 2 < 48) STAGE_W(cur, (t + 2) * 32);
#pragma unroll
    for (int mi = 0; mi < 4; ++mi)
#pragma unroll
      for (int ni = 0; ni < 4; ++ni)
        acc[mi][ni] = __builtin_amdgcn_mfma_f32_16x16x32_bf16(af[mi], bg[ni], acc[mi][ni], 0, 0, 0);
    if (t + 2 < 48) asm volatile("s_waitcnt vmcnt(4)" ::: "memory");
    else            asm volatile("s_waitcnt vmcnt(0)" ::: "memory");
    __builtin_amdgcn_s_barrier();
  }
#undef STAGE_W
  float* C = z ? C1 : C0;
  const int cl = lane & 15, rg = lane >> 4;
#pragma unroll
  for (int mi = 0; mi < 4; ++mi) {
#pragma unroll
    for (int r = 0; r < 4; ++r) {
      const int row = row0 + wr * 64 + mi * 16 + rg * 4 + r;
#pragma unroll
      for (int ni = 0; ni < 4; ++ni) {
        const int c = col0 + wc * 64 + ni * 16 + cl;
        C[(size_t)row * HDIM + c] = acc[mi][ni][r] + (z ? 0.f : bias[c]);
      }
    }
  }
}

// ============ two-partial add + residual + LayerNorm ============
__global__ __launch_bounds__(256) void add2_ln_kernel(
    const float* __restrict__ X1, const float* __restrict__ X2,
    const float* __restrict__ R, const float* __restrict__ g,
    const float* __restrict__ bb, float* __restrict__ out)
{
  const int t = blockIdx.x;
  const int tid = threadIdx.x;
  const float* x1 = X1 + (size_t)t * HDIM;
  const float* x2 = X2 + (size_t)t * HDIM;
  const float* r = R + (size_t)t * HDIM;
  float v[3];
  float sum = 0.f, ssq = 0.f;
#pragma unroll
  for (int i = 0; i < 3; ++i) {
    const float val = x1[tid + i * 256] + x2[tid + i * 256] + r[tid + i * 256];
    v[i] = val;
    sum += val;
    ssq += val * val;
  }
#pragma unroll
  for (int o = 32; o > 0; o >>= 1) {
    sum += __shfl_down(sum, o);
    ssq += __shfl_down(ssq, o);
  }
  __shared__ float red[10];
  const int wid = tid >> 6, lane = tid & 63;
  if (lane == 0) { red[wid] = sum; red[4 + wid] = ssq; }
  __syncthreads();
  if (tid == 0) {
    const float s = red[0] + red[1] + red[2] + red[3];
    const float q = red[4] + red[5] + red[6] + red[7];
    const float mean = s * (1.f / HDIM);
    const float var = q * (1.f / HDIM) - mean * mean;
    red[8] = mean;
    red[9] = rsqrtf(fmaxf(var, 0.f) + 1e-12f);
  }
  __syncthreads();
  const float mean = red[8], rstd = red[9];
#pragma unroll
  for (int i = 0; i < 3; ++i) {
    const int idx = tid + i * 256;
    out[(size_t)t * HDIM + idx] = g[idx] * (v[i] - mean) * rstd + bb[idx];
  }
}

// ============ LN1 variant: also emits bf16 copy (fuses convert_bf16) ============
__global__ __launch_bounds__(256) void add2_ln_bf16_kernel(
    const float* __restrict__ X1, const float* __restrict__ X2,
    const float* __restrict__ R, const float* __restrict__ g,
    const float* __restrict__ bb, float* __restrict__ out, short* __restrict__ outb)
{
  const int t = blockIdx.x;
  const int tid = threadIdx.x;
  const float* x1 = X1 + (size_t)t * HDIM;
  const float* x2 = X2 + (size_t)t * HDIM;
  const float* r = R + (size_t)t * HDIM;
  float v[3];
  float sum = 0.f, ssq = 0.f;
#pragma unroll
  for (int i = 0; i < 3; ++i) {
    const float val = x1[tid + i * 256] + x2[tid + i * 256] + r[tid + i * 256];
    v[i] = val;
    sum += val;
    ssq += val * val;
  }
#pragma unroll
  for (int o = 32; o > 0; o >>= 1) {
    sum += __shfl_down(sum, o);
    ssq += __shfl_down(ssq, o);
  }
  __shared__ float red[10];
  const int wid = tid >> 6, lane = tid & 63;
  if (lane == 0) { red[wid] = sum; red[4 + wid] = ssq; }
  __syncthreads();
  if (tid == 0) {
    const float s = red[0] + red[1] + red[2] + red[3];
    const float q = red[4] + red[5] + red[6] + red[7];
    const float mean = s * (1.f / HDIM);
    const float var = q * (1.f / HDIM) - mean * mean;
    red[8] = mean;
    red[9] = rsqrtf(fmaxf(var, 0.f) + 1e-12f);
  }
  __syncthreads();
  const float mean = red[8], rstd = red[9];
#pragma unroll
  for (int i = 0; i < 3; ++i) {
    const int idx = tid + i * 256;
    const float o = g[idx] * (v[i] - mean) * rstd + bb[idx];
    out[(size_t)t * HDIM + idx] = o;
    outb[(size_t)t * HDIM + idx] = f2bf(o);
  }
}

// ============ router (f32 — keeps argmax path bit-identical) ============
__global__ __launch_bounds__(256) void router_kernel(
    const float* __restrict__ X, const float* __restrict__ Wr,
    const float* __restrict__ br, float* __restrict__ scores_out,
    int* __restrict__ expert, int* __restrict__ counts)
{
  const int wid = threadIdx.x >> 6, lane = threadIdx.x & 63;
  const int tok = blockIdx.x * 4 + wid;
  const float* x = X + (size_t)tok * HDIM;
  float acc[8] = {};
  for (int k0 = 0; k0 < HDIM; k0 += 64) {
    const float xv = x[k0 + lane];
    const float* wrow = Wr + (size_t)(k0 + lane) * NEXP;
    const float4 w0 = *reinterpret_cast<const float4*>(wrow);
    const float4 w1 = *reinterpret_cast<const float4*>(wrow + 4);
    acc[0] = fmaf(xv, w0.x, acc[0]);
    acc[1] = fmaf(xv, w0.y, acc[1]);
    acc[2] = fmaf(xv, w0.z, acc[2]);
    acc[3] = fmaf(xv, w0.w, acc[3]);
    acc[4] = fmaf(xv, w1.x, acc[4]);
    acc[5] = fmaf(xv, w1.y, acc[5]);
    acc[6] = fmaf(xv, w1.z, acc[6]);
    acc[7] = fmaf(xv, w1.w, acc[7]);
  }
#pragma unroll
  for (int e = 0; e < 8; ++e)
#pragma unroll
    for (int o = 32; o > 0; o >>= 1) acc[e] += __shfl_down(acc[e], o);
  if (lane == 0) {
    float mx = -3.0e38f;
#pragma unroll
    for (int e = 0; e < 8; ++e) { acc[e] += br[e]; mx = fmaxf(mx, acc[e]); }
    float sum = 0.f;
#pragma unroll
    for (int e = 0; e < 8; ++e) { acc[e] = expf(acc[e] - mx); sum += acc[e]; }
    const float inv = 1.f / sum;
    int best = 0;
    float bv = acc[0];
#pragma unroll
    for (int e = 0; e < 8; ++e) {
      const float p = acc[e] * inv;
      scores_out[(size_t)tok * NEXP + e] = p;
      if (acc[e] > bv) { bv = acc[e]; best = e; }
    }
    expert[tok] = best;
    atomicAdd(&counts[best], 1);
  }
}

// padded prefix: each expert segment rounded up to a multiple of 128
__global__ void offsets_kernel(const int* __restrict__ counts, int* __restrict__ offs)
{
  if (threadIdx.x == 0 && blockIdx.x == 0) {
    int a = 0;
    for (int e = 0; e < NEXP; ++e) {
      offs[e] = a;
      a += ((counts[e] + 127) >> 7) << 7;
    }
    offs[NEXP] = a;
  }
}

__global__ __launch_bounds__(256) void scatter_kernel(
    const int* __restrict__ expert, const int* __restrict__ offs,
    int* __restrict__ cursor, int* __restrict__ perm)
{
  const int t = blockIdx.x * 256 + threadIdx.x;
  if (t >= TOKS) return;
  const int e = expert[t];
  const int pos = atomicAdd(&cursor[e], 1);
  perm[offs[e] + pos] = t;
}

extern "C" void kernel_launch(void* const* d_in, const int* in_sizes, int n_in,
                              void* d_out, int out_size, void* d_ws, size_t ws_size,
                              hipStream_t stream) {
  const float* hidden = (const float*)d_in[0];
  const float* Wq  = (const float*)d_in[1];
  const float* bq  = (const float*)d_in[2];
  const float* Wk  = (const float*)d_in[3];
  const float* bk  = (const float*)d_in[4];
  const float* Wv  = (const float*)d_in[5];
  const float* bv  = (const float*)d_in[6];
  const float* Wao = (const float*)d_in[7];
  const float* bao = (const float*)d_in[8];
  const float* ln1g = (const float*)d_in[9];
  const float* ln1b = (const float*)d_in[10];
  const float* Wr  = (const float*)d_in[11];
  const float* br  = (const float*)d_in[12];
  const float* Wi  = (const float*)d_in[13];
  const float* bi  = (const float*)d_in[14];
  const float* Wo  = (const float*)d_in[15];
  const float* bo  = (const float*)d_in[16];
  const float* ln2g = (const float*)d_in[17];
  const float* ln2b = (const float*)d_in[18];

  float* out = (float*)d_out;
  float* scores_out = out + (size_t)TOKS * HDIM;

  const size_t M1 = (size_t)TOKS * HDIM;     // 6.29M floats
  const size_t HW = (size_t)HDIM * HDIM;
  float* ws = (float*)d_ws;
  // ---- arena (float offsets, by liveness) ----
  short* QKhb = (short*)ws;
  short* QKlb = (short*)(ws + M1);
  short* VThb = (short*)(ws + 2 * M1);
  short* VTlb = VThb + (size_t)BATCH * NHEAD * 64 * 1024;
  float* O0b  = ws + 3 * M1;
  float* O1b  = ws + 4 * M1;
  float* bqkv = ws + 3 * M1;                 // dead before attention writes O0
  short* Hh = (short*)(ws + 4 * M1);
  short* Hl = Hh + M1;
  short* Ch = (short*)(ws + 2 * M1);         // ctx split (VT region, dead after attention)
  short* Cl = Ch + M1;
  short* wt = (short*)(ws + 5 * M1);
  short* WqkvhT = wt;
  short* WqkvlT = wt + 3 * HW;
  short* WaohT  = wt + 6 * HW;
  short* WaolT  = wt + 7 * HW;
  float2* ml0 = (float2*)(ws + 5 * M1 + 4 * HW);
  float2* ml1 = ml0 + (size_t)BATCH * NHEAD * SEQ;
  float* aoproj0  = ws;                      // QKhb region (dead after attention)
  float* aoproj1  = ws + 3 * M1;             // O0 region (dead after combine)
  float* attn_out = ws + M1;                 // QKlb region
  float* tmp2a    = ws;
  float* tmp2b    = ws + 3 * M1;
  short* Abf    = (short*)(ws + 2 * M1);     // expert phase (Ch/Cl dead after AO)
  short* WiT    = Abf + M1;
  short* WoT    = WiT + (size_t)NEXP * FDIM * HDIM;
  short* interb = WoT + (size_t)HDIM * FDIM;
  int* ints   = (int*)(interb + (size_t)TOKS * FDIM);
  int* perm   = ints;                        // PERMSZ (padded)
  int* expert = ints + PERMSZ;
  int* counts = expert + TOKS;
  int* offs   = counts + NEXP;               // NEXP+1 padded prefix
  int* cursor = offs + NEXP + 1;

  hipMemsetAsync(counts, 0, (NEXP + NEXP + 1 + NEXP) * sizeof(int), stream);
  hipMemsetAsync(perm, 0xFF, PERMSZ * sizeof(int), stream);   // pads = -1
  hipMemcpyAsync(bqkv,        bq, HDIM * sizeof(float), hipMemcpyDeviceToDevice, stream);
  hipMemcpyAsync(bqkv + 768,  bk, HDIM * sizeof(float), hipMemcpyDeviceToDevice, stream);
  hipMemcpyAsync(bqkv + 1536, bv, HDIM * sizeof(float), hipMemcpyDeviceToDevice, stream);

  const dim3 blk(256);
  // --- split prep ---
  convert_split<<<dim3(TOKS * HDIM / 4 / 256), blk, 0, stream>>>(hidden, Hh, Hl, TOKS * HDIM / 4);
  transpose_split<<<dim3(24, 24), blk, 0, stream>>>(Wq,  WqkvhT,          WqkvlT,          HDIM, HDIM);
  transpose_split<<<dim3(24, 24), blk, 0, stream>>>(Wk,  WqkvhT + HW,     WqkvlT + HW,     HDIM, HDIM);
  transpose_split<<<dim3(24, 24), blk, 0, stream>>>(Wv,  WqkvhT + 2 * HW, WqkvlT + 2 * HW, HDIM, HDIM);
  transpose_split<<<dim3(24, 24), blk, 0, stream>>>(Wao, WaohT,           WaolT,           HDIM, HDIM);

  // --- fused QKV projection (depth-2 counted-vmcnt pipeline + XCD swizzle) ---
  qkv_split_mfma<<<dim3(2304 / 128, TOKS / 128), blk, 0, stream>>>(
      Hh, Hl, WqkvhT, WqkvlT, bqkv, QKhb, QKlb, VThb, VTlb);

  // --- MFMA flash attention (bf16 P, Kh-only QK), KV-split x2, 2-wave blocks ---
  attention_part<<<dim3((SEQ / 64) * 2, NHEAD, BATCH), dim3(128), 0, stream>>>(
      QKhb, QKlb, VThb, VTlb, O0b, O1b, ml0, ml1);
  combine_split<<<dim3(TOKS), blk, 0, stream>>>(O0b, O1b, ml0, ml1, Ch, Cl);

  // --- AO projection (single-buf 32KB, split-K x2) + LN1 (fused bf16 emit -> Abf) ---
  gemm_splitk_staged<<<dim3(HDIM / 128, TOKS / 128, 2), blk, 0, stream>>>(
      Ch, Cl, WaohT, WaolT, bao, aoproj0, aoproj1, HDIM, HDIM);
  add2_ln_bf16_kernel<<<dim3(TOKS), blk, 0, stream>>>(
      aoproj0, aoproj1, hidden, ln1g, ln1b, attn_out, Abf);

  // --- router + dispatch (padded permutation) ---
  router_kernel<<<dim3(TOKS / 4), blk, 0, stream>>>(attn_out, Wr, br, scores_out, expert, counts);
  offsets_kernel<<<dim3(1), dim3(64), 0, stream>>>(counts, offs);
  scatter_kernel<<<dim3(TOKS / 256), blk, 0, stream>>>(expert, offs, cursor, perm);

  // --- expert FFN (depth-2 pipelines on 24/48-step loops; fast-tanh GELU) ---
  transpose_to_bf16<<<dim3(FDIM / 32, HDIM / 32, NEXP), blk, 0, stream>>>(Wi, WiT, HDIM, FDIM);
  transpose_to_bf16<<<dim3(HDIM / 32, FDIM / 32, 1), blk, 0, stream>>>(Wo, WoT, FDIM, HDIM);

  expert_up_mfma<<<dim3(PERMSZ / 128, FDIM / 128), blk, 0, stream>>>(
      Abf, WiT, bi, perm, offs, interb);
  wo_mfma<<<dim3(HDIM / 128, TOKS / 128, 2), blk, 0, stream>>>(interb, WoT, bo, tmp2a, tmp2b);
  add2_ln_kernel<<<dim3(TOKS), blk, 0, stream>>>(tmp2a, tmp2b, attn_out, ln2g, ln2b, out);
}